// Round 1
// baseline (8782.313 us; speedup 1.0000x reference)
//
#include <hip/hip_runtime.h>
#include <hip/hip_bf16.h>

// Problem constants (fixed by the reference)
#define TT 2      // node types
#define RR 4      // relations
#define LL 2      // layers
#define DIN 16
#define HH 256
#define CC 128
#define DOUT 4
#define EPS 1e-5f

// ---------------------------------------------------------------------------
// count node types
__global__ __launch_bounds__(256) void k_count(const int* __restrict__ nt, int* __restrict__ counts, int n) {
    __shared__ int c[TT];
    if (threadIdx.x < TT) c[threadIdx.x] = 0;
    __syncthreads();
    for (long long i = (long long)blockIdx.x * blockDim.x + threadIdx.x; i < n;
         i += (long long)gridDim.x * blockDim.x) {
        atomicAdd(&c[nt[(int)i]], 1);
    }
    __syncthreads();
    if (threadIdx.x < TT) atomicAdd(&counts[threadIdx.x], c[threadIdx.x]);
}

// ---------------------------------------------------------------------------
// BN statistics: block = F threads, each block handles `chunk` nodes.
template <int F>
__global__ void k_bn_stats(const float* __restrict__ X, const int* __restrict__ nt,
                           float* __restrict__ sums, float* __restrict__ sumsq, int n, int chunk) {
    const int f = threadIdx.x;
    const int i0 = blockIdx.x * chunk;
    const int i1 = min(n, i0 + chunk);
    float s0 = 0.f, s1 = 0.f, q0 = 0.f, q1 = 0.f;
    for (int i = i0; i < i1; ++i) {
        const int t = nt[i];
        const float v = X[(size_t)i * F + f];
        if (t == 0) { s0 += v; q0 += v * v; }
        else        { s1 += v; q1 += v * v; }
    }
    atomicAdd(&sums[f], s0);
    atomicAdd(&sums[F + f], s1);
    atomicAdd(&sumsq[f], q0);
    atomicAdd(&sumsq[F + f], q1);
}

// BN apply (+ optional leaky relu), float4 elementwise
template <int F, bool LEAKY>
__global__ __launch_bounds__(256) void k_bn_apply(const float* __restrict__ X, float* __restrict__ Y,
                                                  const int* __restrict__ nt,
                                                  const float* __restrict__ sums,
                                                  const float* __restrict__ sumsq,
                                                  const int* __restrict__ counts,
                                                  const float* __restrict__ g,
                                                  const float* __restrict__ be, int n) {
    constexpr int FC = F / 4;
    const long long total = (long long)n * FC;
    for (long long gid = (long long)blockIdx.x * blockDim.x + threadIdx.x; gid < total;
         gid += (long long)gridDim.x * blockDim.x) {
        const int i = (int)(gid / FC);
        const int c = (int)(gid % FC);
        const int t = nt[i];
        const float cnt = fmaxf((float)counts[t], 1.f);
        const float inv = 1.f / cnt;
        const float4 x = *(const float4*)(X + (size_t)i * F + c * 4);
        const float4 s = *(const float4*)(sums + t * F + c * 4);
        const float4 q = *(const float4*)(sumsq + t * F + c * 4);
        const float4 gg = *(const float4*)(g + t * F + c * 4);
        const float4 bb = *(const float4*)(be + t * F + c * 4);
        float xs[4] = {x.x, x.y, x.z, x.w};
        float ss[4] = {s.x, s.y, s.z, s.w};
        float qs[4] = {q.x, q.y, q.z, q.w};
        float gs[4] = {gg.x, gg.y, gg.z, gg.w};
        float bs[4] = {bb.x, bb.y, bb.z, bb.w};
        float o[4];
#pragma unroll
        for (int j = 0; j < 4; ++j) {
            const float mean = ss[j] * inv;
            const float var = qs[j] * inv - mean * mean;
            const float r = rsqrtf(var + EPS);
            float v = (xs[j] - mean) * r * gs[j] + bs[j];
            if (LEAKY) v = v > 0.f ? v : 0.01f * v;
            o[j] = v;
        }
        *(float4*)(Y + (size_t)i * F + c * 4) = make_float4(o[0], o[1], o[2], o[3]);
    }
}

// ---------------------------------------------------------------------------
// Generic (hetero-)GEMM: Y[i] (=/+=) X[i] @ W[type(i)] (+ B[type(i)])
// W layout: [TPL][K][MOUT], B layout: [TPL][MOUT]
template <int K, int MOUT, bool HET, bool ACC, bool BIAS>
__global__ __launch_bounds__(256) void k_gemm(const float* __restrict__ X, const int* __restrict__ nt,
                                              const float* __restrict__ W, const float* __restrict__ B,
                                              float* __restrict__ Y, int n) {
    constexpr int BM = 64, BK = 16;
    constexpr int TPL = HET ? TT : 1;
    constexpr int TX = (MOUT >= 16) ? 16 : MOUT;
    constexpr int TY = 256 / TX;
    constexpr int VN = BM / TY;    // nodes per thread
    constexpr int VU = MOUT / TX;  // feats per thread

    __shared__ float As[BM][BK + 1];
    __shared__ float Ws[TPL][BK][MOUT];
    __shared__ int nts[BM];

    const int tid = threadIdx.x;
    const int tx = tid % TX, ty = tid / TX;
    const int n0 = blockIdx.x * BM;

    if (tid < BM) {
        const int i = n0 + tid;
        nts[tid] = (HET && i < n) ? nt[i] : 0;
    }
    __syncthreads();

    int tt[VN];
#pragma unroll
    for (int v = 0; v < VN; ++v) tt[v] = HET ? nts[ty * VN + v] : 0;

    float acc[VN][VU];
#pragma unroll
    for (int v = 0; v < VN; ++v)
#pragma unroll
        for (int u = 0; u < VU; ++u) acc[v][u] = 0.f;

    for (int k0 = 0; k0 < K; k0 += BK) {
        // stage A tile
#pragma unroll
        for (int e = tid; e < BM * BK; e += 256) {
            const int m = e >> 4, kk = e & 15;
            const int i = n0 + m;
            As[m][kk] = (i < n) ? X[(size_t)i * K + k0 + kk] : 0.f;
        }
        // stage W tiles (all types)
        constexpr int WTOT = TPL * BK * MOUT;
        for (int e = tid; e < WTOT; e += 256) {
            const int f = e % MOUT;
            const int kk = (e / MOUT) % BK;
            const int t = e / (MOUT * BK);
            Ws[t][kk][f] = W[(size_t)t * K * MOUT + (size_t)(k0 + kk) * MOUT + f];
        }
        __syncthreads();
#pragma unroll
        for (int kk = 0; kk < BK; ++kk) {
            float a[VN];
#pragma unroll
            for (int v = 0; v < VN; ++v) a[v] = As[ty * VN + v][kk];
#pragma unroll
            for (int u = 0; u < VU; ++u) {
                const float w0 = Ws[0][kk][tx + TX * u];
                const float w1 = HET ? Ws[TPL - 1][kk][tx + TX * u] : w0;
#pragma unroll
                for (int v = 0; v < VN; ++v) {
                    const float w = (HET && tt[v]) ? w1 : w0;
                    acc[v][u] += a[v] * w;
                }
            }
        }
        __syncthreads();
    }

#pragma unroll
    for (int v = 0; v < VN; ++v) {
        const int i = n0 + ty * VN + v;
        if (i >= n) continue;
#pragma unroll
        for (int u = 0; u < VU; ++u) {
            const int f = tx + TX * u;
            float val = acc[v][u];
            if (BIAS) val += HET ? B[tt[v] * MOUT + f] : B[f];
            const size_t o = (size_t)i * MOUT + f;
            if (ACC) Y[o] += val;
            else Y[o] = val;
        }
    }
}

// ---------------------------------------------------------------------------
// edge scatter for one relation: agg[dst] += hs[src] for matching edges
__global__ __launch_bounds__(256) void k_scatter(const float* __restrict__ hs, const int* __restrict__ src,
                                                 const int* __restrict__ dst, const int* __restrict__ et,
                                                 float* __restrict__ agg, int rel, int nE) {
    const long long gid = (long long)blockIdx.x * blockDim.x + threadIdx.x;
    const int e = (int)(gid >> 5);
    const int c = (int)(gid & 31);
    if (e >= nE) return;
    if (et[e] != rel) return;
    const float4 v = *(const float4*)(hs + (size_t)src[e] * CC + c * 4);
    float* p = agg + (size_t)dst[e] * CC + c * 4;
    atomicAdd(p + 0, v.x);
    atomicAdd(p + 1, v.y);
    atomicAdd(p + 2, v.z);
    atomicAdd(p + 3, v.w);
}

// elementwise A += B over n4 float4s
__global__ __launch_bounds__(256) void k_add(float* __restrict__ A, const float* __restrict__ Bv, long long n4) {
    for (long long i = (long long)blockIdx.x * blockDim.x + threadIdx.x; i < n4;
         i += (long long)gridDim.x * blockDim.x) {
        float4 a = ((float4*)A)[i];
        const float4 b = ((const float4*)Bv)[i];
        a.x += b.x; a.y += b.y; a.z += b.z; a.w += b.w;
        ((float4*)A)[i] = a;
    }
}

// ---------------------------------------------------------------------------
extern "C" void kernel_launch(void* const* d_in, const int* in_sizes, int n_in,
                              void* d_out, int out_size, void* d_ws, size_t ws_size,
                              hipStream_t stream) {
    const float* x = (const float*)d_in[0];
    const int* ei = (const int*)d_in[1];
    const int* nt = (const int*)d_in[2];
    const int* et = (const int*)d_in[3];
    const float* ri_w0 = (const float*)d_in[4];
    const float* ri_b0 = (const float*)d_in[5];
    const float* ri_g0 = (const float*)d_in[6];
    const float* ri_be0 = (const float*)d_in[7];
    const float* ri_w1 = (const float*)d_in[8];
    const float* ri_b1 = (const float*)d_in[9];
    const float* cn_g = (const float*)d_in[10];
    const float* cn_b = (const float*)d_in[11];
    const float* rg_w = (const float*)d_in[12];
    const float* rg_root = (const float*)d_in[13];
    const float* rg_bias = (const float*)d_in[14];
    const float* mn_g = (const float*)d_in[15];
    const float* mn_b = (const float*)d_in[16];
    const float* mw0 = (const float*)d_in[17];
    const float* mb0 = (const float*)d_in[18];
    const float* mg0 = (const float*)d_in[19];
    const float* mbe0 = (const float*)d_in[20];
    const float* mw1 = (const float*)d_in[21];
    const float* mb1 = (const float*)d_in[22];
    const float* ro_w0 = (const float*)d_in[23];
    const float* ro_b0 = (const float*)d_in[24];
    const float* ro_g0 = (const float*)d_in[25];
    const float* ro_be0 = (const float*)d_in[26];
    const float* ro_w1 = (const float*)d_in[27];
    const float* ro_b1 = (const float*)d_in[28];

    const int n = in_sizes[2];       // N nodes
    const int nE = in_sizes[3];      // E edges
    const int* src = ei;
    const int* dst = ei + nE;

    // workspace layout
    char* w = (char*)d_ws;
    const size_t szA = (size_t)n * HH * sizeof(float);   // N x 256
    const size_t szC = (size_t)n * CC * sizeof(float);   // N x 128
    float* A256 = (float*)w;                 // readin/MLP hidden (N x 256)
    float* agg = A256;                       // alias: conv aggregation (N x 128)
    float* tmp = A256 + (size_t)n * CC;      // alias: per-relation hs  (N x 128)
    float* h = (float*)(w + szA);            // residual stream (N x 128)
    float* y = (float*)(w + szA + szC);      // BN output / t128 (N x 128)
    char* statp = w + szA + 2 * szC;
    float* sums = (float*)statp;             // 2*256 floats
    float* sumsq = sums + TT * HH;           // 2*256 floats
    int* counts = (int*)(sumsq + TT * HH);
    const size_t needed = szA + 2 * szC + (2 * TT * HH) * sizeof(float) + 64;
    if (ws_size < needed) return;

    float* out = (float*)d_out;

    const int gGemm = (n + 63) / 64;
    const int gStat = (n + 127) / 128;
    const long long n4c = (long long)n * CC / 4;

    // node-type counts (once)
    hipMemsetAsync(counts, 0, TT * sizeof(int), stream);
    k_count<<<512, 256, 0, stream>>>(nt, counts, n);

    auto bn256 = [&](const float* X, float* Y, const float* g, const float* be) {
        hipMemsetAsync(sums, 0, 2 * TT * HH * sizeof(float), stream);
        k_bn_stats<HH><<<gStat, HH, 0, stream>>>(X, nt, sums, sumsq, n, 128);
        k_bn_apply<HH, true><<<2048, 256, 0, stream>>>(X, Y, nt, sums, sumsq, counts, g, be, n);
    };
    auto bn128 = [&](const float* X, float* Y, const float* g, const float* be) {
        hipMemsetAsync(sums, 0, 2 * TT * HH * sizeof(float), stream);
        k_bn_stats<CC><<<gStat, CC, 0, stream>>>(X, nt, sums, sumsq, n, 128);
        k_bn_apply<CC, true><<<2048, 256, 0, stream>>>(X, Y, nt, sums, sumsq, counts, g, be, n);
    };

    // ---- readin MLP ----
    k_gemm<DIN, HH, true, false, true><<<gGemm, 256, 0, stream>>>(x, nt, ri_w0, ri_b0, A256, n);
    bn256(A256, A256, ri_g0, ri_be0);
    k_gemm<HH, CC, true, false, true><<<gGemm, 256, 0, stream>>>(A256, nt, ri_w1, ri_b1, h, n);

    // ---- RES+ blocks ----
    for (int l = 0; l < LL; ++l) {
        // conv block: y = act(bn(h)); h += agg(msgs) + y@root + bias
        bn128(h, y, cn_g + (size_t)l * TT * CC, cn_b + (size_t)l * TT * CC);
        hipMemsetAsync(agg, 0, szC, stream);
        for (int r = 0; r < RR; ++r) {
            const float* Wr = rg_w + ((size_t)l * RR + r) * CC * CC;
            k_gemm<CC, CC, false, false, false><<<gGemm, 256, 0, stream>>>(y, nullptr, Wr, nullptr, tmp, n);
            const long long gs = ((long long)nE * (CC / 4) + 255) / 256;
            k_scatter<<<(int)gs, 256, 0, stream>>>(tmp, src, dst, et, agg, r, nE);
        }
        k_gemm<CC, CC, false, true, true><<<gGemm, 256, 0, stream>>>(
            y, nullptr, rg_root + (size_t)l * CC * CC, rg_bias + (size_t)l * CC, agg, n);
        k_add<<<2048, 256, 0, stream>>>(h, agg, n4c);

        // MLP block: y = act(bn(h)); t256 = y@mw0; t256=act(bn(t256)); y=t256@mw1; h+=y
        bn128(h, y, mn_g + (size_t)l * TT * CC, mn_b + (size_t)l * TT * CC);
        k_gemm<CC, HH, true, false, true><<<gGemm, 256, 0, stream>>>(
            y, nt, mw0 + (size_t)l * TT * CC * HH, mb0 + (size_t)l * TT * HH, A256, n);
        bn256(A256, A256, mg0 + (size_t)l * TT * HH, mbe0 + (size_t)l * TT * HH);
        k_gemm<HH, CC, true, false, true><<<gGemm, 256, 0, stream>>>(
            A256, nt, mw1 + (size_t)l * TT * HH * CC, mb1 + (size_t)l * TT * CC, y, n);
        k_add<<<2048, 256, 0, stream>>>(h, y, n4c);
    }

    // ---- readout ----
    k_gemm<CC, HH, true, false, true><<<gGemm, 256, 0, stream>>>(h, nt, ro_w0, ro_b0, A256, n);
    bn256(A256, A256, ro_g0, ro_be0);
    k_gemm<HH, DOUT, true, false, true><<<gGemm, 256, 0, stream>>>(A256, nt, ro_w1, ro_b1, out, n);
}

// Round 2
// 3407.109 us; speedup vs baseline: 2.5776x; 2.5776x over previous
//
#include <hip/hip_runtime.h>

#define TT 2
#define RR 4
#define LL 2
#define DIN 16
#define HH 256
#define CC 128
#define DOUT 4
#define EPS 1e-5f

typedef float v4f __attribute__((ext_vector_type(4)));

// ---------------------------------------------------------------------------
__global__ __launch_bounds__(256) void k_count(const int* __restrict__ nt, int* __restrict__ counts, int n) {
    __shared__ int c[TT];
    if (threadIdx.x < TT) c[threadIdx.x] = 0;
    __syncthreads();
    for (long long i = (long long)blockIdx.x * blockDim.x + threadIdx.x; i < n;
         i += (long long)gridDim.x * blockDim.x)
        atomicAdd(&c[nt[(int)i]], 1);
    __syncthreads();
    if (threadIdx.x < TT) atomicAdd(&counts[threadIdx.x], c[threadIdx.x]);
}

__global__ void k_typestart(const int* __restrict__ counts, int* __restrict__ typeStart,
                            int* __restrict__ pcur, int n) {
    typeStart[0] = 0; typeStart[1] = counts[0]; typeStart[2] = n;
    pcur[0] = 0; pcur[1] = counts[0];
}

__global__ __launch_bounds__(256) void k_fill_perm(const int* __restrict__ nt, int* __restrict__ pcur,
                                                   int* __restrict__ perm, int n) {
    const int i = blockIdx.x * 256 + threadIdx.x;
    if (i < n) {
        const int t = nt[i];
        const int p = atomicAdd(&pcur[t], 1);
        perm[p] = i;
    }
}

__global__ __launch_bounds__(256) void k_deg(const int* __restrict__ dstv, int* __restrict__ rowp, int nE) {
    const int e = blockIdx.x * 256 + threadIdx.x;
    if (e < nE) atomicAdd(&rowp[dstv[e]], 1);
}

__global__ __launch_bounds__(1024) void k_scan1(int* __restrict__ rowp, int* __restrict__ part, int n) {
    __shared__ int sm[1024];
    const int tid = threadIdx.x;
    const int i = blockIdx.x * 1024 + tid;
    const int v = (i < n) ? rowp[i] : 0;
    sm[tid] = v;
    __syncthreads();
    for (int off = 1; off < 1024; off <<= 1) {
        const int u = (tid >= off) ? sm[tid - off] : 0;
        __syncthreads();
        sm[tid] += u;
        __syncthreads();
    }
    if (i < n) rowp[i] = sm[tid] - v;     // block-local exclusive
    if (tid == 1023) part[blockIdx.x] = sm[1023];
}

__global__ __launch_bounds__(1024) void k_scan2(int* __restrict__ part, int nb) {
    __shared__ int sm[1024];
    const int tid = threadIdx.x;
    const int v = (tid < nb) ? part[tid] : 0;
    sm[tid] = v;
    __syncthreads();
    for (int off = 1; off < 1024; off <<= 1) {
        const int u = (tid >= off) ? sm[tid - off] : 0;
        __syncthreads();
        sm[tid] += u;
        __syncthreads();
    }
    if (tid < nb) part[tid] = sm[tid] - v;  // exclusive
    if (tid == nb - 1) part[nb] = sm[tid];  // total
}

__global__ __launch_bounds__(1024) void k_scan3(int* __restrict__ rowp, const int* __restrict__ part,
                                                int n, int nb) {
    const int i = blockIdx.x * 1024 + threadIdx.x;
    if (i < n) rowp[i] += part[i >> 10];
    else if (i == n) rowp[n] = part[nb];
}

// csr entry: src (20b) | rel<<20 (2b) | src_type<<22 (1b)
__global__ __launch_bounds__(256) void k_fill_csr(const int* __restrict__ srcv, const int* __restrict__ dstv,
                                                  const int* __restrict__ et, const int* __restrict__ nt,
                                                  int* __restrict__ cursor, int* __restrict__ csr, int nE) {
    const int e = blockIdx.x * 256 + threadIdx.x;
    if (e < nE) {
        const int d = dstv[e];
        const int pos = atomicAdd(&cursor[d], 1);
        const int s = srcv[e];
        csr[pos] = s | (et[e] << 20) | (nt[s] << 22);
    }
}

// ---------------------------------------------------------------------------
// BN statistics, float4, block covers CH=1024 rows
template <int F>
__global__ __launch_bounds__(256) void k_stats(const float* __restrict__ X, const int* __restrict__ nt,
                                               float* __restrict__ sums, float* __restrict__ sumsq, int n) {
    constexpr int CG = F / 4;
    constexpr int RS = 256 / CG;
    const int c = threadIdx.x % CG;
    const int rs = threadIdx.x / CG;
    v4f s0 = 0.f, s1 = 0.f, q0 = 0.f, q1 = 0.f;
    const int i0 = blockIdx.x * 1024;
    const int i1 = min(n, i0 + 1024);
    for (int i = i0 + rs; i < i1; i += RS) {
        const int t = nt[i];
        const v4f v = *(const v4f*)(X + (size_t)i * F + 4 * c);
        if (t == 0) { s0 += v; q0 += v * v; }
        else        { s1 += v; q1 += v * v; }
    }
#pragma unroll
    for (int j = 0; j < 4; ++j) {
        atomicAdd(&sums[4 * c + j], s0[j]);
        atomicAdd(&sums[F + 4 * c + j], s1[j]);
        atomicAdd(&sumsq[4 * c + j], q0[j]);
        atomicAdd(&sumsq[F + 4 * c + j], q1[j]);
    }
}

template <int F>
__global__ __launch_bounds__(256) void k_coef(const float* __restrict__ sums, const float* __restrict__ sumsq,
                                              const int* __restrict__ counts, const float* __restrict__ g,
                                              const float* __restrict__ be, float* __restrict__ scale,
                                              float* __restrict__ shift) {
    const int tid = blockIdx.x * 256 + threadIdx.x;
    if (tid >= TT * F) return;
    const int t = tid / F;
    const float cnt = fmaxf((float)counts[t], 1.f);
    const float mean = sums[tid] / cnt;
    const float var = sumsq[tid] / cnt - mean * mean;
    const float inv = rsqrtf(var + EPS);
    const float sc = g[tid] * inv;
    scale[tid] = sc;
    shift[tid] = be[tid] - mean * sc;
}

// ---------------------------------------------------------------------------
// per-node relation aggregation with inline BN+leaky on gathered h values.
// one wave per destination node; lane l owns feature cols {2l, 2l+1}.
__global__ __launch_bounds__(256) void k_agg1(const float* __restrict__ h, const int* __restrict__ rowp,
                                              const int* __restrict__ csr, const float* __restrict__ scale,
                                              const float* __restrict__ shift, float* __restrict__ agg,
                                              int n, int rel) {
    const int wid = threadIdx.x >> 6;
    const int lane = threadIdx.x & 63;
    const int i = blockIdx.x * 4 + wid;
    if (i >= n) return;
    const int c = 2 * lane;
    const float sc0x = scale[c],      sc0y = scale[c + 1];
    const float sf0x = shift[c],      sf0y = shift[c + 1];
    const float sc1x = scale[CC + c], sc1y = scale[CC + c + 1];
    const float sf1x = shift[CC + c], sf1y = shift[CC + c + 1];
    float ax = 0.f, ay = 0.f;
    const int e0 = rowp[i], e1 = rowp[i + 1];
    for (int e = e0; e < e1; e += 32) {
        const int cnt = min(32, e1 - e);
        int pk = 0;
        if (lane < cnt) pk = csr[e + lane];
        for (int j = 0; j < cnt; ++j) {
            const int p = __shfl(pk, j);
            if (((p >> 20) & 3) != rel) continue;
            const int src = p & 0xFFFFF;
            const int tb = (p >> 22) & 1;
            const float2 v = *(const float2*)(h + (size_t)src * CC + c);
            float vx = fmaf(v.x, tb ? sc1x : sc0x, tb ? sf1x : sf0x);
            float vy = fmaf(v.y, tb ? sc1y : sc0y, tb ? sf1y : sf0y);
            vx = fmaxf(vx, 0.01f * vx);
            vy = fmaxf(vy, 0.01f * vy);
            ax += vx; ay += vy;
        }
    }
    *(float2*)(agg + (size_t)i * CC + c) = make_float2(ax, ay);
}

// ---------------------------------------------------------------------------
// Tiled GEMM, type-uniform per block (PERM: gridDim.y = T, rows via perm[]).
// Y[row] (=/+=) act?(bnin?(X[row]))@W[t] (+ B[t])
template <int K, int MOUT, bool PERM, bool WHET, bool ACC, bool BIAS, bool BNIN>
__global__ __launch_bounds__(256) void k_gemm(const float* __restrict__ X, const int* __restrict__ perm,
                                              const int* __restrict__ typeStart, const float* __restrict__ W,
                                              const float* __restrict__ B, const float* __restrict__ scale,
                                              const float* __restrict__ shift, float* __restrict__ Y, int n) {
    constexpr int BM = 64, BK = 16;
    constexpr int TX = (MOUT >= 64) ? 16 : MOUT;  // 16 (MOUT>=64) or 4
    constexpr int TY = 256 / TX;
    constexpr int VN = BM / TY;                   // 4 or 1
    constexpr int VU = MOUT / TX;                 // 16 / 8 / 1
    constexpr int WQ = BK * MOUT / 4;
    constexpr int WR = (WQ + 255) / 256;

    __shared__ float As[BK][BM];
    __shared__ float Ws[BK][MOUT];
    __shared__ float csh[BNIN ? K : 1];
    __shared__ float cfh[BNIN ? K : 1];

    const int tid = threadIdx.x;
    const int tx = tid % TX, ty = tid / TX;

    int t = 0, rbeg = 0, rend = n;
    if (PERM) {
        t = blockIdx.y;
        rbeg = typeStart[t];
        rend = typeStart[t + 1];
    }
    const int r0 = rbeg + blockIdx.x * BM;
    if (r0 >= rend) return;

    const float* Wp = W + (WHET ? (size_t)t * K * MOUT : 0);

    if (BNIN) {
        for (int k = tid; k < K; k += 256) {
            csh[k] = scale[t * K + k];
            cfh[k] = shift[t * K + k];
        }
    }
    __syncthreads();

    // staging map: thread -> (row sm_, k-quad skg)
    const int sm_ = tid >> 2, skg = tid & 3;
    const int sgi = r0 + sm_;
    const bool svalid = sgi < rend;
    const int sri = svalid ? (PERM ? perm[sgi] : sgi) : 0;

    float acc[VN][VU];
#pragma unroll
    for (int v = 0; v < VN; ++v)
#pragma unroll
        for (int u = 0; u < VU; ++u) acc[v][u] = 0.f;

    for (int k0 = 0; k0 < K; k0 += BK) {
        // prefetch A + W for this k-tile into registers
        v4f a4 = 0.f;
        if (svalid) a4 = *(const v4f*)(X + (size_t)sri * K + k0 + skg * 4);
        if (BNIN) {
#pragma unroll
            for (int j = 0; j < 4; ++j) {
                const float vv = a4[j] * csh[k0 + skg * 4 + j] + cfh[k0 + skg * 4 + j];
                a4[j] = fmaxf(vv, 0.01f * vv);
            }
        }
        v4f wreg[WR];
#pragma unroll
        for (int q = 0; q < WR; ++q) {
            const int idx = tid + q * 256;
            if (idx < WQ) wreg[q] = *(const v4f*)(Wp + (size_t)k0 * MOUT + idx * 4);
        }
        __syncthreads();
#pragma unroll
        for (int j = 0; j < 4; ++j) As[skg * 4 + j][sm_] = a4[j];
#pragma unroll
        for (int q = 0; q < WR; ++q) {
            const int idx = tid + q * 256;
            if (idx < WQ) *(v4f*)(&Ws[0][0] + idx * 4) = wreg[q];
        }
        __syncthreads();

#pragma unroll
        for (int kk = 0; kk < BK; ++kk) {
            float a[VN];
            if constexpr (VN == 4) {
                const v4f av = *(const v4f*)&As[kk][ty * 4];
                a[0] = av[0]; a[1] = av[1]; a[2] = av[2]; a[3] = av[3];
            } else {
                a[0] = As[kk][ty];
            }
            if constexpr (VU % 4 == 0) {
#pragma unroll
                for (int uq = 0; uq < VU / 4; ++uq) {
                    const v4f wv = *(const v4f*)&Ws[kk][uq * (TX * 4) + tx * 4];
#pragma unroll
                    for (int v = 0; v < VN; ++v)
#pragma unroll
                        for (int j = 0; j < 4; ++j) acc[v][uq * 4 + j] += a[v] * wv[j];
                }
            } else {
                const float wv = Ws[kk][tx];
#pragma unroll
                for (int v = 0; v < VN; ++v) acc[v][0] += a[v] * wv;
            }
        }
        __syncthreads();
    }

    const float* Bp = B + (WHET ? (size_t)t * MOUT : 0);
#pragma unroll
    for (int v = 0; v < VN; ++v) {
        const int gi = r0 + ty * VN + v;
        if (gi >= rend) continue;
        const int ri = PERM ? perm[gi] : gi;
        float* yp = Y + (size_t)ri * MOUT;
        if constexpr (VU % 4 == 0) {
#pragma unroll
            for (int uq = 0; uq < VU / 4; ++uq) {
                const int cb = uq * (TX * 4) + tx * 4;
                v4f o;
#pragma unroll
                for (int j = 0; j < 4; ++j) o[j] = acc[v][uq * 4 + j];
                if (BIAS) o += *(const v4f*)(Bp + cb);
                if (ACC) o += *(const v4f*)(yp + cb);
                *(v4f*)(yp + cb) = o;
            }
        } else {
            float o = acc[v][0];
            if (BIAS) o += Bp[tx];
            if (ACC) o += yp[tx];
            yp[tx] = o;
        }
    }
}

__global__ __launch_bounds__(256) void k_add(float* __restrict__ A, const float* __restrict__ Bv, long long n4) {
    for (long long i = (long long)blockIdx.x * blockDim.x + threadIdx.x; i < n4;
         i += (long long)gridDim.x * blockDim.x) {
        v4f a = ((v4f*)A)[i];
        a += ((const v4f*)Bv)[i];
        ((v4f*)A)[i] = a;
    }
}

// ---------------------------------------------------------------------------
extern "C" void kernel_launch(void* const* d_in, const int* in_sizes, int n_in,
                              void* d_out, int out_size, void* d_ws, size_t ws_size,
                              hipStream_t stream) {
    const float* x = (const float*)d_in[0];
    const int* ei = (const int*)d_in[1];
    const int* nt = (const int*)d_in[2];
    const int* et = (const int*)d_in[3];
    const float* ri_w0 = (const float*)d_in[4];
    const float* ri_b0 = (const float*)d_in[5];
    const float* ri_g0 = (const float*)d_in[6];
    const float* ri_be0 = (const float*)d_in[7];
    const float* ri_w1 = (const float*)d_in[8];
    const float* ri_b1 = (const float*)d_in[9];
    const float* cn_g = (const float*)d_in[10];
    const float* cn_b = (const float*)d_in[11];
    const float* rg_w = (const float*)d_in[12];
    const float* rg_root = (const float*)d_in[13];
    const float* rg_bias = (const float*)d_in[14];
    const float* mn_g = (const float*)d_in[15];
    const float* mn_b = (const float*)d_in[16];
    const float* mw0 = (const float*)d_in[17];
    const float* mb0 = (const float*)d_in[18];
    const float* mg0 = (const float*)d_in[19];
    const float* mbe0 = (const float*)d_in[20];
    const float* mw1 = (const float*)d_in[21];
    const float* mb1 = (const float*)d_in[22];
    const float* ro_w0 = (const float*)d_in[23];
    const float* ro_b0 = (const float*)d_in[24];
    const float* ro_g0 = (const float*)d_in[25];
    const float* ro_be0 = (const float*)d_in[26];
    const float* ro_w1 = (const float*)d_in[27];
    const float* ro_b1 = (const float*)d_in[28];

    const int n = in_sizes[2];
    const int nE = in_sizes[3];
    const int* srcv = ei;
    const int* dstv = ei + nE;

    // ---- workspace layout ----
    char* w = (char*)d_ws;
    size_t off = 0;
    auto alloc = [&](size_t bytes) -> char* {
        char* p = w + off;
        off = (off + bytes + 255) & ~(size_t)255;
        return p;
    };
    float* region1 = (float*)alloc((size_t)n * HH * sizeof(float)); // A256 | agg1+conv_acc
    float* h = (float*)alloc((size_t)n * CC * sizeof(float));
    int* csr = (int*)alloc((size_t)nE * sizeof(int));
    int* rowp = (int*)alloc((size_t)(n + 1) * sizeof(int));
    int* perm = (int*)alloc((size_t)n * sizeof(int));
    int* meta = (int*)alloc(16 * sizeof(int));       // counts[2], pcur[2], typeStart[3]
    int* part = (int*)alloc(160 * sizeof(int));
    float* stats = (float*)alloc(1024 * sizeof(float)); // sums[512] | sumsq[512]
    float* scale = (float*)alloc(512 * sizeof(float));
    float* shift = (float*)alloc(512 * sizeof(float));
    if (ws_size < off) return;

    int* counts = meta;
    int* pcur = meta + 2;
    int* typeStart = meta + 4;
    float* sums = stats;
    float* sumsq = stats + 512;
    float* agg1 = region1;
    float* conv_acc = region1 + (size_t)n * CC;
    float* A256 = region1;
    int* cursor = (int*)d_out;  // scratch during setup; overwritten by final gemm
    float* out = (float*)d_out;

    const int gE = (nE + 255) / 256;
    const int gN = (n + 255) / 256;
    const int nb = (n + 1023) / 1024;
    const int nsb = (n + 1023) / 1024;
    const dim3 gP((n + 63) / 64, 2);
    const dim3 gU((n + 63) / 64, 1);
    const long long n4c = (long long)n * CC / 4;
    const size_t szC = (size_t)n * CC * sizeof(float);

    // ---- setup: counts, perm, CSR ----
    hipMemsetAsync(meta, 0, 16 * sizeof(int), stream);
    k_count<<<512, 256, 0, stream>>>(nt, counts, n);
    k_typestart<<<1, 1, 0, stream>>>(counts, typeStart, pcur, n);
    k_fill_perm<<<gN, 256, 0, stream>>>(nt, pcur, perm, n);
    hipMemsetAsync(rowp, 0, (size_t)(n + 1) * sizeof(int), stream);
    k_deg<<<gE, 256, 0, stream>>>(dstv, rowp, nE);
    k_scan1<<<nb, 1024, 0, stream>>>(rowp, part, n);
    k_scan2<<<1, 1024, 0, stream>>>(part, nb);
    k_scan3<<<(n + 1024) / 1024, 1024, 0, stream>>>(rowp, part, n, nb);
    hipMemcpyAsync(cursor, rowp, (size_t)n * sizeof(int), hipMemcpyDeviceToDevice, stream);
    k_fill_csr<<<gE, 256, 0, stream>>>(srcv, dstv, et, nt, cursor, csr, nE);

    auto stats_coef = [&](const float* X, int F, const float* g, const float* be) {
        hipMemsetAsync(stats, 0, 1024 * sizeof(float), stream);
        if (F == HH) {
            k_stats<HH><<<nsb, 256, 0, stream>>>(X, nt, sums, sumsq, n);
            k_coef<HH><<<2, 256, 0, stream>>>(sums, sumsq, counts, g, be, scale, shift);
        } else {
            k_stats<CC><<<nsb, 256, 0, stream>>>(X, nt, sums, sumsq, n);
            k_coef<CC><<<1, 256, 0, stream>>>(sums, sumsq, counts, g, be, scale, shift);
        }
    };

    // ---- readin ----
    k_gemm<DIN, HH, true, true, false, true, false><<<gP, 256, 0, stream>>>(
        x, perm, typeStart, ri_w0, ri_b0, nullptr, nullptr, A256, n);
    stats_coef(A256, HH, ri_g0, ri_be0);
    k_gemm<HH, CC, true, true, false, true, true><<<gP, 256, 0, stream>>>(
        A256, perm, typeStart, ri_w1, ri_b1, scale, shift, h, n);

    // ---- RES+ layers ----
    for (int l = 0; l < LL; ++l) {
        // conv: conv_acc = sum_r agg_r@W_r + bn(h)@root + bias ; h += conv_acc
        stats_coef(h, CC, cn_g + (size_t)l * TT * CC, cn_b + (size_t)l * TT * CC);
        hipMemsetAsync(conv_acc, 0, szC, stream);
        for (int r = 0; r < RR; ++r) {
            k_agg1<<<(n + 3) / 4, 256, 0, stream>>>(h, rowp, csr, scale, shift, agg1, n, r);
            k_gemm<CC, CC, false, false, true, false, false><<<gU, 256, 0, stream>>>(
                agg1, nullptr, nullptr, rg_w + ((size_t)l * RR + r) * CC * CC, nullptr,
                nullptr, nullptr, conv_acc, n);
        }
        k_gemm<CC, CC, true, false, true, true, true><<<gP, 256, 0, stream>>>(
            h, perm, typeStart, rg_root + (size_t)l * CC * CC, rg_bias + (size_t)l * CC,
            scale, shift, conv_acc, n);
        k_add<<<2048, 256, 0, stream>>>(h, conv_acc, n4c);

        // MLP: h += W1 @ act(bn(W0 @ act(bn(h))))
        stats_coef(h, CC, mn_g + (size_t)l * TT * CC, mn_b + (size_t)l * TT * CC);
        k_gemm<CC, HH, true, true, false, true, true><<<gP, 256, 0, stream>>>(
            h, perm, typeStart, mw0 + (size_t)l * TT * CC * HH, mb0 + (size_t)l * TT * HH,
            scale, shift, A256, n);
        stats_coef(A256, HH, mg0 + (size_t)l * TT * HH, mbe0 + (size_t)l * TT * HH);
        k_gemm<HH, CC, true, true, true, true, true><<<gP, 256, 0, stream>>>(
            A256, perm, typeStart, mw1 + (size_t)l * TT * HH * CC, mb1 + (size_t)l * TT * CC,
            scale, shift, h, n);
    }

    // ---- readout ----
    k_gemm<CC, HH, true, true, false, true, false><<<gP, 256, 0, stream>>>(
        h, perm, typeStart, ro_w0, ro_b0, nullptr, nullptr, A256, n);
    stats_coef(A256, HH, ro_g0, ro_be0);
    k_gemm<HH, DOUT, true, true, false, true, true><<<gP, 256, 0, stream>>>(
        A256, perm, typeStart, ro_w1, ro_b1, scale, shift, out, n);
}

// Round 3
// 2160.255 us; speedup vs baseline: 4.0654x; 1.5772x over previous
//
#include <hip/hip_runtime.h>

#define TT 2
#define RR 4
#define LL 2
#define DIN 16
#define HH 256
#define CC 128
#define DOUT 4
#define EPS 1e-5f

typedef float v4f __attribute__((ext_vector_type(4)));

// ---------------------------------------------------------------------------
// generic scan kernels (1024-block hierarchical exclusive scan)
__global__ __launch_bounds__(1024) void k_scan1(const int* __restrict__ in, int* __restrict__ out,
                                                int* __restrict__ part, int n) {
    __shared__ int sm[1024];
    const int tid = threadIdx.x;
    const int i = blockIdx.x * 1024 + tid;
    const int v = (i < n) ? in[i] : 0;
    sm[tid] = v;
    __syncthreads();
    for (int off = 1; off < 1024; off <<= 1) {
        const int u = (tid >= off) ? sm[tid - off] : 0;
        __syncthreads();
        sm[tid] += u;
        __syncthreads();
    }
    if (i < n) out[i] = sm[tid] - v;
    if (tid == 1023) part[blockIdx.x] = sm[1023];
}

__global__ __launch_bounds__(1024) void k_scan2(int* __restrict__ part, int nb) {
    __shared__ int sm[1024];
    const int tid = threadIdx.x;
    const int v = (tid < nb) ? part[tid] : 0;
    sm[tid] = v;
    __syncthreads();
    for (int off = 1; off < 1024; off <<= 1) {
        const int u = (tid >= off) ? sm[tid - off] : 0;
        __syncthreads();
        sm[tid] += u;
        __syncthreads();
    }
    if (tid < nb) part[tid] = sm[tid] - v;
    if (tid == nb - 1) part[nb] = sm[tid];
}

__global__ __launch_bounds__(1024) void k_scan3(int* __restrict__ arr, const int* __restrict__ part,
                                                int n, int nb) {
    const int i = blockIdx.x * 1024 + threadIdx.x;
    if (i < n) arr[i] += part[i >> 10];
    else if (i == n) arr[n] = part[nb];
}

__global__ void k_meta(const int* __restrict__ pscan, int* __restrict__ typeStart, int n) {
    const int c1 = pscan[n];
    typeStart[0] = 0; typeStart[1] = n - c1; typeStart[2] = n;
}

__global__ __launch_bounds__(256) void k_build_perm(const int* __restrict__ nt, const int* __restrict__ pscan,
                                                    const int* __restrict__ typeStart, int* __restrict__ perm,
                                                    int* __restrict__ inv, int n) {
    const int i = blockIdx.x * 256 + threadIdx.x;
    if (i >= n) return;
    const int s1 = pscan[i];
    const int pos = nt[i] ? (typeStart[1] + s1) : (i - s1);
    perm[pos] = i;
    inv[i] = pos;
}

__global__ __launch_bounds__(256) void k_deg2(const int* __restrict__ dstv, const int* __restrict__ et,
                                              const int* __restrict__ inv, int* __restrict__ rowp2, int nE) {
    const int e = blockIdx.x * 256 + threadIdx.x;
    if (e < nE) atomicAdd(&rowp2[inv[dstv[e]] * 4 + et[e]], 1);
}

__global__ __launch_bounds__(256) void k_fill2(const int* __restrict__ srcv, const int* __restrict__ dstv,
                                               const int* __restrict__ et, const int* __restrict__ inv,
                                               int* __restrict__ cur, int* __restrict__ csr, int nE) {
    const int e = blockIdx.x * 256 + threadIdx.x;
    if (e < nE) {
        const int pos = atomicAdd(&cur[inv[dstv[e]] * 4 + et[e]], 1);
        csr[pos] = inv[srcv[e]];
    }
}

// ---------------------------------------------------------------------------
// BN coefficient build: scale = g*rsqrt(var+eps), shift = be - mean*scale
__global__ __launch_bounds__(512) void k_coef(const float* __restrict__ ssum, const float* __restrict__ ssq,
                                              const int* __restrict__ typeStart, const float* __restrict__ g,
                                              const float* __restrict__ be, float* __restrict__ scale,
                                              float* __restrict__ shift, int F) {
    const int tid = threadIdx.x;
    if (tid >= TT * F) return;
    const int t = tid / F;
    const float cnt = fmaxf((float)(typeStart[t + 1] - typeStart[t]), 1.f);
    const float mean = ssum[tid] / cnt;
    const float var = ssq[tid] / cnt - mean * mean;
    const float sc = g[tid] * rsqrtf(var + EPS);
    scale[tid] = sc;
    shift[tid] = be[tid] - mean * sc;
}

// ---------------------------------------------------------------------------
// per-(node,rel) aggregation with inline BN+leaky; wave per node, lane owns 2 cols
__global__ __launch_bounds__(256) void k_agg1(const float* __restrict__ h, const int* __restrict__ rowp2,
                                              const int* __restrict__ csr, const float* __restrict__ scale,
                                              const float* __restrict__ shift, const int* __restrict__ typeStart,
                                              float* __restrict__ aggP, int n, int rel) {
    const int wid = threadIdx.x >> 6, lane = threadIdx.x & 63;
    const int i = blockIdx.x * 4 + wid;
    if (i >= n) return;
    const int c = 2 * lane;
    const int c0 = typeStart[1];
    const float2 sa0 = *(const float2*)(scale + c);
    const float2 sb0 = *(const float2*)(shift + c);
    const float2 sa1 = *(const float2*)(scale + CC + c);
    const float2 sb1 = *(const float2*)(shift + CC + c);
    const int e0 = rowp2[i * 4 + rel];
    const int e1 = rowp2[i * 4 + rel + 1];
    float ax = 0.f, ay = 0.f;
    for (int e = e0; e < e1; e += 64) {
        const int cnt = min(64, e1 - e);
        int pk = (lane < cnt) ? csr[e + lane] : 0;
        for (int j = 0; j < cnt; ++j) {
            const int s = __shfl(pk, j);
            const bool tb = s >= c0;
            const float2 v = *(const float2*)(h + (size_t)s * CC + c);
            float vx = fmaf(v.x, tb ? sa1.x : sa0.x, tb ? sb1.x : sb0.x);
            float vy = fmaf(v.y, tb ? sa1.y : sa0.y, tb ? sb1.y : sb0.y);
            vx = fmaxf(vx, 0.01f * vx);
            vy = fmaxf(vy, 0.01f * vy);
            ax += vx; ay += vy;
        }
    }
    *(float2*)(aggP + (size_t)i * CC + c) = make_float2(ax, ay);
}

// ---------------------------------------------------------------------------
// fused residual add + BN stats: h += tc; accumulate per-type col sums/sumsq
__global__ __launch_bounds__(256) void k_add_stats(float* __restrict__ h, const float* __restrict__ tc,
                                                   const int* __restrict__ typeStart, float* __restrict__ ssum,
                                                   float* __restrict__ ssq, int n) {
    __shared__ float red[256 * 17];
    const int tid = threadIdx.x;
    const int c = tid & 31;
    const int rs = tid >> 5;
    const int c0 = typeStart[1];
    const int i0 = blockIdx.x * 256;
    const int i1 = min(n, i0 + 256);
    v4f s0 = 0.f, q0 = 0.f, s1 = 0.f, q1 = 0.f;
    for (int i = i0 + rs; i < i1; i += 8) {
        v4f a = *(const v4f*)(h + (size_t)i * CC + 4 * c);
        a += *(const v4f*)(tc + (size_t)i * CC + 4 * c);
        *(v4f*)(h + (size_t)i * CC + 4 * c) = a;
        if (i < c0) { s0 += a; q0 += a * a; }
        else        { s1 += a; q1 += a * a; }
    }
#pragma unroll
    for (int j = 0; j < 4; ++j) {
        red[tid * 17 + j] = s0[j];
        red[tid * 17 + 4 + j] = q0[j];
        red[tid * 17 + 8 + j] = s1[j];
        red[tid * 17 + 12 + j] = q1[j];
    }
    __syncthreads();
    for (int o = tid; o < 512; o += 256) {
        const int col = o & 127, m = (o >> 7) & 1, t = (o >> 8) & 1;
        const int reg = t * 8 + m * 4 + (col & 3);
        float v = 0.f;
#pragma unroll
        for (int r = 0; r < 8; ++r) v += red[((col >> 2) + 32 * r) * 17 + reg];
        atomicAdd((m ? ssq : ssum) + t * CC + col, v);
    }
}

// ---------------------------------------------------------------------------
// Tiled GEMM. Rows are dense in permuted space; TYPED: blockIdx.y = type with
// [typeStart[t], typeStart[t+1]) row range. GIN: gather X rows via perm (readin).
// SCOUT: scatter Y rows via perm (readout). BNIN: apply scale/shift+leaky to X.
// STATS: accumulate per-type column sums/sumsq of final output.
template <int K, int MOUT, bool TYPED, bool GIN, bool SCOUT, bool WHET,
          bool ACC, bool BIAS, bool BNIN, bool STATS>
__global__ __launch_bounds__(256) void k_gemm(
    const float* __restrict__ X, const int* __restrict__ perm,
    const int* __restrict__ typeStart, const float* __restrict__ W,
    const float* __restrict__ B, const float* __restrict__ scale,
    const float* __restrict__ shift, float* __restrict__ Y,
    float* __restrict__ ssum, float* __restrict__ ssq, int n) {
    constexpr int BK = 16;
    constexpr int BM = (MOUT == 128) ? 128 : 64;
    constexpr int TX = (MOUT >= 64) ? 16 : MOUT;
    constexpr int TY = 256 / TX;
    constexpr int VN = BM / TY;
    constexpr int VU = MOUT / TX;
    constexpr int NT = K / BK;
    constexpr int WQ = BK * MOUT / 4;
    constexpr int WR = (WQ + 255) / 256;
    constexpr int AV = (BM == 128) ? 2 : 1;

    __shared__ float As[BK][BM];
    __shared__ float Ws[BK][MOUT];
    __shared__ float csh[BNIN ? K : 1];
    __shared__ float cfh[BNIN ? K : 1];
    __shared__ float lsum[STATS ? MOUT : 1];
    __shared__ float lsq[STATS ? MOUT : 1];

    const int tid = threadIdx.x;
    const int tx = tid % TX, ty = tid / TX;

    int t = 0, rbeg = 0, rend = n;
    if constexpr (TYPED) {
        t = blockIdx.y;
        rbeg = typeStart[t];
        rend = typeStart[t + 1];
    }
    const int r0 = rbeg + blockIdx.x * BM;
    if (r0 >= rend) return;

    const float* Wp = W + (WHET ? (size_t)t * K * MOUT : 0);

    if constexpr (BNIN) {
        for (int k = tid; k < K; k += 256) {
            csh[k] = scale[t * K + k];
            cfh[k] = shift[t * K + k];
        }
    }
    if constexpr (STATS) {
        for (int k = tid; k < MOUT; k += 256) { lsum[k] = 0.f; lsq[k] = 0.f; }
    }
    __syncthreads();

    const int srow = (BM == 128) ? (tid >> 1) : (tid >> 2);
    const int skq = (BM == 128) ? ((tid & 1) * 2) : (tid & 3);
    const int sgi = r0 + srow;
    const bool svalid = sgi < rend;
    const int sri = svalid ? (GIN ? perm[sgi] : sgi) : 0;
    const float* xrow = X + (size_t)sri * K;

    float acc[VN][VU];
#pragma unroll
    for (int v = 0; v < VN; ++v)
#pragma unroll
        for (int u = 0; u < VU; ++u) acc[v][u] = 0.f;

    for (int kt = 0; kt < NT; ++kt) {
        const int k0 = kt * BK;
        v4f areg[AV];
#pragma unroll
        for (int q = 0; q < AV; ++q) {
            areg[q] = 0.f;
            if (svalid) areg[q] = *(const v4f*)(xrow + k0 + (skq + q) * 4);
            if constexpr (BNIN) {
#pragma unroll
                for (int j = 0; j < 4; ++j) {
                    const int k = k0 + (skq + q) * 4 + j;
                    const float vv = fmaf(areg[q][j], csh[k], cfh[k]);
                    areg[q][j] = fmaxf(vv, 0.01f * vv);
                }
            }
        }
        v4f wreg[WR];
#pragma unroll
        for (int q = 0; q < WR; ++q) {
            const int idx = tid + q * 256;
            if (idx < WQ) wreg[q] = *(const v4f*)(Wp + (size_t)k0 * MOUT + (size_t)idx * 4);
        }
        __syncthreads();
#pragma unroll
        for (int q = 0; q < AV; ++q)
#pragma unroll
            for (int j = 0; j < 4; ++j) As[(skq + q) * 4 + j][srow] = areg[q][j];
#pragma unroll
        for (int q = 0; q < WR; ++q) {
            const int idx = tid + q * 256;
            if (idx < WQ) *(v4f*)(&Ws[0][0] + (size_t)idx * 4) = wreg[q];
        }
        __syncthreads();

#pragma unroll
        for (int kk = 0; kk < BK; ++kk) {
            float a[VN];
            if constexpr (BM == 128) {
                const v4f a0 = *(const v4f*)&As[kk][ty * 8];
                const v4f a1 = *(const v4f*)&As[kk][ty * 8 + 4];
#pragma unroll
                for (int j = 0; j < 4; ++j) { a[j] = a0[j]; a[4 + j] = a1[j]; }
            } else if constexpr (TX == 16) {
                const v4f av = *(const v4f*)&As[kk][ty * 4];
#pragma unroll
                for (int j = 0; j < 4; ++j) a[j] = av[j];
            } else {
                a[0] = As[kk][ty];
            }
            if constexpr (MOUT >= 64) {
#pragma unroll
                for (int uq = 0; uq < VU / 4; ++uq) {
                    const v4f wv = *(const v4f*)&Ws[kk][uq * 64 + tx * 4];
#pragma unroll
                    for (int v = 0; v < VN; ++v)
#pragma unroll
                        for (int j = 0; j < 4; ++j) acc[v][uq * 4 + j] += a[v] * wv[j];
                }
            } else {
                const float wv = Ws[kk][tx];
#pragma unroll
                for (int v = 0; v < VN; ++v) acc[v][0] += a[v] * wv;
            }
        }
        __syncthreads();
    }

    const float* Bp = B + (WHET ? (size_t)t * MOUT : 0);
    float csum[STATS ? VU : 1], csq[STATS ? VU : 1];
    if constexpr (STATS) {
#pragma unroll
        for (int u = 0; u < VU; ++u) { csum[u] = 0.f; csq[u] = 0.f; }
    }
#pragma unroll
    for (int v = 0; v < VN; ++v) {
        const int gi = r0 + ty * VN + v;
        if (gi >= rend) continue;
        float* yp = Y + (size_t)(SCOUT ? perm[gi] : gi) * MOUT;
        if constexpr (MOUT >= 64) {
#pragma unroll
            for (int uq = 0; uq < VU / 4; ++uq) {
                const int cb = uq * 64 + tx * 4;
                v4f o;
#pragma unroll
                for (int j = 0; j < 4; ++j) o[j] = acc[v][uq * 4 + j];
                if (BIAS) o += *(const v4f*)(Bp + cb);
                if (ACC) o += *(const v4f*)(yp + cb);
                *(v4f*)(yp + cb) = o;
                if constexpr (STATS) {
#pragma unroll
                    for (int j = 0; j < 4; ++j) {
                        csum[uq * 4 + j] += o[j];
                        csq[uq * 4 + j] += o[j] * o[j];
                    }
                }
            }
        } else {
            float o = acc[v][0];
            if (BIAS) o += Bp[tx];
            if (ACC) o += yp[tx];
            yp[tx] = o;
        }
    }
    if constexpr (STATS) {
#pragma unroll
        for (int u = 0; u < VU; ++u) {
            const int col = (u >> 2) * 64 + tx * 4 + (u & 3);
            atomicAdd(&lsum[col], csum[u]);
            atomicAdd(&lsq[col], csq[u]);
        }
        __syncthreads();
        for (int col = tid; col < MOUT; col += 256) {
            atomicAdd(&ssum[t * MOUT + col], lsum[col]);
            atomicAdd(&ssq[t * MOUT + col], lsq[col]);
        }
    }
}

// ---------------------------------------------------------------------------
extern "C" void kernel_launch(void* const* d_in, const int* in_sizes, int n_in,
                              void* d_out, int out_size, void* d_ws, size_t ws_size,
                              hipStream_t stream) {
    const float* x = (const float*)d_in[0];
    const int* ei = (const int*)d_in[1];
    const int* nt = (const int*)d_in[2];
    const int* et = (const int*)d_in[3];
    const float* ri_w0 = (const float*)d_in[4];
    const float* ri_b0 = (const float*)d_in[5];
    const float* ri_g0 = (const float*)d_in[6];
    const float* ri_be0 = (const float*)d_in[7];
    const float* ri_w1 = (const float*)d_in[8];
    const float* ri_b1 = (const float*)d_in[9];
    const float* cn_g = (const float*)d_in[10];
    const float* cn_b = (const float*)d_in[11];
    const float* rg_w = (const float*)d_in[12];
    const float* rg_root = (const float*)d_in[13];
    const float* rg_bias = (const float*)d_in[14];
    const float* mn_g = (const float*)d_in[15];
    const float* mn_b = (const float*)d_in[16];
    const float* mw0 = (const float*)d_in[17];
    const float* mb0 = (const float*)d_in[18];
    const float* mg0 = (const float*)d_in[19];
    const float* mbe0 = (const float*)d_in[20];
    const float* mw1 = (const float*)d_in[21];
    const float* mb1 = (const float*)d_in[22];
    const float* ro_w0 = (const float*)d_in[23];
    const float* ro_b0 = (const float*)d_in[24];
    const float* ro_g0 = (const float*)d_in[25];
    const float* ro_be0 = (const float*)d_in[26];
    const float* ro_w1 = (const float*)d_in[27];
    const float* ro_b1 = (const float*)d_in[28];

    const int n = in_sizes[2];
    const int nE = in_sizes[3];
    const int* srcv = ei;
    const int* dstv = ei + nE;

    // ---- workspace ----
    char* w = (char*)d_ws;
    size_t off = 0;
    auto alloc = [&](size_t bytes) -> char* {
        char* p = w + off;
        off = (off + bytes + 255) & ~(size_t)255;
        return p;
    };
    float* region1 = (float*)alloc((size_t)n * HH * sizeof(float)); // A256 | aggP+tconv
    float* h = (float*)alloc((size_t)n * CC * sizeof(float));
    int* csr = (int*)alloc((size_t)nE * sizeof(int));
    int* rowp2 = (int*)alloc(((size_t)4 * n + 1) * sizeof(int));
    int* perm = (int*)alloc((size_t)n * sizeof(int));
    int* inv = (int*)alloc((size_t)n * sizeof(int));
    int* pscan = (int*)alloc((size_t)(n + 1) * sizeof(int));
    int* part = (int*)alloc(1032 * sizeof(int));
    int* typeStart = (int*)alloc(64);
    float* statbuf = (float*)alloc(10 * 1024 * sizeof(float));
    float* scale = (float*)alloc(512 * sizeof(float));
    float* shift = (float*)alloc(512 * sizeof(float));
    if (ws_size < off) return;

    float* A256 = region1;
    float* aggP = region1;                       // conv phase: [n][128]
    float* tconv = region1 + (size_t)n * CC;     // conv phase: [n][128]
    int* cur2 = (int*)region1;                   // setup phase only
    float* out = (float*)d_out;

    auto SS = [&](int slot) { return statbuf + (size_t)slot * 1024; };
    auto SQ = [&](int slot) { return statbuf + (size_t)slot * 1024 + 512; };

    const int gE = (nE + 255) / 256;
    const int gN = (n + 255) / 256;
    const int nb = (n + 1023) / 1024;
    const int m4 = 4 * n;
    const int nb2 = (m4 + 1023) / 1024;
    const dim3 g128((n + 127) / 128, 2);
    const dim3 g64((n + 63) / 64, 2);
    const dim3 g128u((n + 127) / 128, 1);

    // ---- setup: type partition (scan, no atomics) + CSR by (dst,rel) ----
    hipMemsetAsync(statbuf, 0, 10 * 1024 * sizeof(float), stream);
    k_scan1<<<nb, 1024, 0, stream>>>(nt, pscan, part, n);
    k_scan2<<<1, 1024, 0, stream>>>(part, nb);
    k_scan3<<<(n + 1024) / 1024, 1024, 0, stream>>>(pscan, part, n, nb);
    k_meta<<<1, 1, 0, stream>>>(pscan, typeStart, n);
    k_build_perm<<<gN, 256, 0, stream>>>(nt, pscan, typeStart, perm, inv, n);
    hipMemsetAsync(rowp2, 0, ((size_t)m4 + 1) * sizeof(int), stream);
    k_deg2<<<gE, 256, 0, stream>>>(dstv, et, inv, rowp2, nE);
    k_scan1<<<nb2, 1024, 0, stream>>>(rowp2, rowp2, part, m4);
    k_scan2<<<1, 1024, 0, stream>>>(part, nb2);
    k_scan3<<<(m4 + 1024) / 1024, 1024, 0, stream>>>(rowp2, part, m4, nb2);
    hipMemcpyAsync(cur2, rowp2, (size_t)m4 * sizeof(int), hipMemcpyDeviceToDevice, stream);
    k_fill2<<<gE, 256, 0, stream>>>(srcv, dstv, et, inv, cur2, csr, nE);

    // ---- readin ----
    k_gemm<DIN, HH, true, true, false, true, false, true, false, true><<<g64, 256, 0, stream>>>(
        x, perm, typeStart, ri_w0, ri_b0, nullptr, nullptr, A256, SS(0), SQ(0), n);
    k_coef<<<1, 512, 0, stream>>>(SS(0), SQ(0), typeStart, ri_g0, ri_be0, scale, shift, HH);
    k_gemm<HH, CC, true, false, false, true, false, true, true, true><<<g128, 256, 0, stream>>>(
        A256, nullptr, typeStart, ri_w1, ri_b1, scale, shift, h, SS(1), SQ(1), n);

    // ---- RES+ layers ----
    for (int l = 0; l < LL; ++l) {
        const int s_cn = l ? 4 : 1, s_mn = l ? 5 : 2, s_mg = l ? 6 : 3, s_nx = l ? 7 : 4;
        // conv: tconv = bn(h)@root + bias + sum_r agg_r@W_r ; h += tconv (fused mn stats)
        k_coef<<<1, 512, 0, stream>>>(SS(s_cn), SQ(s_cn), typeStart,
                                      cn_g + (size_t)l * TT * CC, cn_b + (size_t)l * TT * CC,
                                      scale, shift, CC);
        k_gemm<CC, CC, true, false, false, false, false, true, true, false><<<g128, 256, 0, stream>>>(
            h, nullptr, typeStart, rg_root + (size_t)l * CC * CC, rg_bias + (size_t)l * CC,
            scale, shift, tconv, nullptr, nullptr, n);
        for (int r = 0; r < RR; ++r) {
            k_agg1<<<(n + 3) / 4, 256, 0, stream>>>(h, rowp2, csr, scale, shift, typeStart, aggP, n, r);
            k_gemm<CC, CC, false, false, false, false, true, false, false, false><<<g128u, 256, 0, stream>>>(
                aggP, nullptr, nullptr, rg_w + ((size_t)l * RR + r) * CC * CC, nullptr,
                nullptr, nullptr, tconv, nullptr, nullptr, n);
        }
        k_add_stats<<<(n + 255) / 256, 256, 0, stream>>>(h, tconv, typeStart, SS(s_mn), SQ(s_mn), n);

        // MLP: h += mw1 @ act(bn(mw0 @ act(bn(h))))
        k_coef<<<1, 512, 0, stream>>>(SS(s_mn), SQ(s_mn), typeStart,
                                      mn_g + (size_t)l * TT * CC, mn_b + (size_t)l * TT * CC,
                                      scale, shift, CC);
        k_gemm<CC, HH, true, false, false, true, false, true, true, true><<<g64, 256, 0, stream>>>(
            h, nullptr, typeStart, mw0 + (size_t)l * TT * CC * HH, mb0 + (size_t)l * TT * HH,
            scale, shift, A256, SS(s_mg), SQ(s_mg), n);
        k_coef<<<1, 512, 0, stream>>>(SS(s_mg), SQ(s_mg), typeStart,
                                      mg0 + (size_t)l * TT * HH, mbe0 + (size_t)l * TT * HH,
                                      scale, shift, HH);
        k_gemm<HH, CC, true, false, false, true, true, true, true, true><<<g128, 256, 0, stream>>>(
            A256, nullptr, typeStart, mw1 + (size_t)l * TT * HH * CC, mb1 + (size_t)l * TT * CC,
            scale, shift, h, SS(s_nx), SQ(s_nx), n);
    }

    // ---- readout ----
    k_gemm<CC, HH, true, false, false, true, false, true, false, true><<<g64, 256, 0, stream>>>(
        h, nullptr, typeStart, ro_w0, ro_b0, nullptr, nullptr, A256, SS(8), SQ(8), n);
    k_coef<<<1, 512, 0, stream>>>(SS(8), SQ(8), typeStart, ro_g0, ro_be0, scale, shift, HH);
    k_gemm<HH, DOUT, true, false, true, true, false, true, true, false><<<g64, 256, 0, stream>>>(
        A256, perm, typeStart, ro_w1, ro_b1, scale, shift, out, nullptr, nullptr, n);
}

// Round 4
// 1260.484 us; speedup vs baseline: 6.9674x; 1.7138x over previous
//
#include <hip/hip_runtime.h>

#define TT 2
#define RR 4
#define LL 2
#define DIN 16
#define HH 256
#define CC 128
#define DOUT 4
#define EPS 1e-5f

typedef float v4f __attribute__((ext_vector_type(4)));
typedef short bf16x8 __attribute__((ext_vector_type(8)));

__device__ __forceinline__ ushort f2bf(float x) {
    uint u = __float_as_uint(x);
    return (ushort)((u + 0x7fffu + ((u >> 16) & 1u)) >> 16);
}
__device__ __forceinline__ float bf2f(ushort h) { return __uint_as_float(((uint)h) << 16); }
__device__ __forceinline__ uint psplit(float x) {
    ushort hi = f2bf(x);
    ushort lo = f2bf(x - bf2f(hi));
    return ((uint)hi << 16) | lo;
}
__device__ __forceinline__ int swc(int c) { return c ^ ((c >> 3) & 7); }

// ---------------------------------------------------------------------------
// hierarchical exclusive scan
__global__ __launch_bounds__(1024) void k_scan1(const int* __restrict__ in, int* __restrict__ out,
                                                int* __restrict__ part, int n) {
    __shared__ int sm[1024];
    const int tid = threadIdx.x;
    const int i = blockIdx.x * 1024 + tid;
    const int v = (i < n) ? in[i] : 0;
    sm[tid] = v;
    __syncthreads();
    for (int off = 1; off < 1024; off <<= 1) {
        const int u = (tid >= off) ? sm[tid - off] : 0;
        __syncthreads();
        sm[tid] += u;
        __syncthreads();
    }
    if (i < n) out[i] = sm[tid] - v;
    if (tid == 1023) part[blockIdx.x] = sm[1023];
}

__global__ __launch_bounds__(1024) void k_scan2(int* __restrict__ part, int nb) {
    __shared__ int sm[1024];
    const int tid = threadIdx.x;
    const int v = (tid < nb) ? part[tid] : 0;
    sm[tid] = v;
    __syncthreads();
    for (int off = 1; off < 1024; off <<= 1) {
        const int u = (tid >= off) ? sm[tid - off] : 0;
        __syncthreads();
        sm[tid] += u;
        __syncthreads();
    }
    if (tid < nb) part[tid] = sm[tid] - v;
    if (tid == nb - 1) part[nb] = sm[tid];
}

__global__ __launch_bounds__(1024) void k_scan3(int* __restrict__ arr, const int* __restrict__ part,
                                                int n, int nb) {
    const int i = blockIdx.x * 1024 + threadIdx.x;
    if (i < n) arr[i] += part[i >> 10];
    else if (i == n) arr[n] = part[nb];
}

__global__ void k_meta(const int* __restrict__ pscan, int* __restrict__ typeStart, int n) {
    const int c1 = pscan[n];
    typeStart[0] = 0; typeStart[1] = n - c1; typeStart[2] = n;
}

__global__ __launch_bounds__(256) void k_build_perm(const int* __restrict__ nt, const int* __restrict__ pscan,
                                                    const int* __restrict__ typeStart, int* __restrict__ perm,
                                                    int* __restrict__ inv, int n) {
    const int i = blockIdx.x * 256 + threadIdx.x;
    if (i >= n) return;
    const int s1 = pscan[i];
    const int pos = nt[i] ? (typeStart[1] + s1) : (i - s1);
    perm[pos] = i;
    inv[i] = pos;
}

__global__ __launch_bounds__(256) void k_deg2(const int* __restrict__ dstv, const int* __restrict__ et,
                                              const int* __restrict__ inv, int* __restrict__ rowp2, int nE) {
    const int e = blockIdx.x * 256 + threadIdx.x;
    if (e < nE) atomicAdd(&rowp2[inv[dstv[e]] * 4 + et[e]], 1);
}

__global__ __launch_bounds__(256) void k_fill2(const int* __restrict__ srcv, const int* __restrict__ dstv,
                                               const int* __restrict__ et, const int* __restrict__ inv,
                                               int* __restrict__ cur, int* __restrict__ csr, int nE) {
    const int e = blockIdx.x * 256 + threadIdx.x;
    if (e < nE) {
        const int pos = atomicAdd(&cur[inv[dstv[e]] * 4 + et[e]], 1);
        csr[pos] = inv[srcv[e]];
    }
}

// ---------------------------------------------------------------------------
// weight packing: [nmat][K][N] f32 -> [mat][K/8][N][8] bf16
__global__ __launch_bounds__(256) void k_pack(const float* __restrict__ src, ushort* __restrict__ dst,
                                              int K, int N, long long total) {
    for (long long idx = (long long)blockIdx.x * 256 + threadIdx.x; idx < total;
         idx += (long long)gridDim.x * 256) {
        const long long kn = (long long)K * N;
        const int mat = (int)(idx / kn);
        const int rem = (int)(idx - mat * kn);
        const int k = rem / N, col = rem % N;
        dst[((size_t)mat * (K / 8) + (k >> 3)) * N * 8 + (size_t)col * 8 + (k & 7)] = f2bf(src[idx]);
    }
}

// conv stacked W: rows 0..511 = rg_w[r][kin][col], rows 512..639 = root[k][col]
__global__ __launch_bounds__(256) void k_pack_conv(const float* __restrict__ rgw, const float* __restrict__ root,
                                                   ushort* __restrict__ dst) {
    const int idx = blockIdx.x * 256 + threadIdx.x;
    if (idx >= 640 * 128) return;
    const int k = idx >> 7, col = idx & 127;
    const float v = (k < 512) ? rgw[(((k >> 7) * CC) + (k & 127)) * CC + col]
                              : root[(size_t)(k - 512) * CC + col];
    dst[((size_t)(k >> 3) * CC + col) * 8 + (k & 7)] = f2bf(v);
}

// ---------------------------------------------------------------------------
__global__ __launch_bounds__(512) void k_coef(const float* __restrict__ ssum, const float* __restrict__ ssq,
                                              const int* __restrict__ typeStart, const float* __restrict__ g,
                                              const float* __restrict__ be, float* __restrict__ scale,
                                              float* __restrict__ shift, int F) {
    const int tid = threadIdx.x;
    if (tid >= TT * F) return;
    const int t = tid / F;
    const float cnt = fmaxf((float)(typeStart[t + 1] - typeStart[t]), 1.f);
    const float mean = ssum[tid] / cnt;
    const float var = ssq[tid] / cnt - mean * mean;
    const float sc = g[tid] * rsqrtf(var + EPS);
    scale[tid] = sc;
    shift[tid] = be[tid] - mean * sc;
}

// ---------------------------------------------------------------------------
// fused 4-relation aggregation + own-node BN: writes pre-split hi/lo packed
// buf[row][640]: cols [r*128..r*128+127] = sum_{e in rel r} bnact(h[src]),
// cols [512..639] = bnact(h[dst]).  wave per dst node, lane owns 2 cols.
__global__ __launch_bounds__(256) void k_agg4(const float* __restrict__ h, const int* __restrict__ rowp2,
                                              const int* __restrict__ csr, const float* __restrict__ scale,
                                              const float* __restrict__ shift, const int* __restrict__ typeStart,
                                              uint* __restrict__ buf, int q0, int q1) {
    const int wid = threadIdx.x >> 6, lane = threadIdx.x & 63;
    const int i = q0 + blockIdx.x * 4 + wid;
    if (i >= q1) return;
    const int c = 2 * lane;
    const int c0 = typeStart[1];
    const float2 sa0 = *(const float2*)(scale + c);
    const float2 sb0 = *(const float2*)(shift + c);
    const float2 sa1 = *(const float2*)(scale + CC + c);
    const float2 sb1 = *(const float2*)(shift + CC + c);
    float2 a0 = {0.f, 0.f}, a1 = {0.f, 0.f}, a2 = {0.f, 0.f}, a3 = {0.f, 0.f};
    const int e0 = rowp2[4 * i], b1 = rowp2[4 * i + 1], b2 = rowp2[4 * i + 2],
              b3 = rowp2[4 * i + 3], e1 = rowp2[4 * i + 4];
    for (int e = e0; e < e1; e += 64) {
        const int cnt = min(64, e1 - e);
        int pk = (lane < cnt) ? csr[e + lane] : 0;
        for (int j = 0; j < cnt; ++j) {
            const int s = __shfl(pk, j);
            const int idx = e + j;  // wave-uniform -> uniform branch below
            const bool tb = s >= c0;
            const float2 v = *(const float2*)(h + (size_t)s * CC + c);
            float vx = fmaf(v.x, tb ? sa1.x : sa0.x, tb ? sb1.x : sb0.x);
            float vy = fmaf(v.y, tb ? sa1.y : sa0.y, tb ? sb1.y : sb0.y);
            vx = fmaxf(vx, 0.01f * vx);
            vy = fmaxf(vy, 0.01f * vy);
            if (idx < b1)      { a0.x += vx; a0.y += vy; }
            else if (idx < b2) { a1.x += vx; a1.y += vy; }
            else if (idx < b3) { a2.x += vx; a2.y += vy; }
            else               { a3.x += vx; a3.y += vy; }
        }
    }
    const bool td = i >= c0;
    const float2 hv = *(const float2*)(h + (size_t)i * CC + c);
    float yx = fmaf(hv.x, td ? sa1.x : sa0.x, td ? sb1.x : sb0.x);
    float yy = fmaf(hv.y, td ? sa1.y : sa0.y, td ? sb1.y : sb0.y);
    yx = fmaxf(yx, 0.01f * yx);
    yy = fmaxf(yy, 0.01f * yy);
    uint* brow = buf + (size_t)(i - q0) * 640;
    uint2 p;
    p.x = psplit(a0.x); p.y = psplit(a0.y); *(uint2*)(brow + 0 * 128 + c) = p;
    p.x = psplit(a1.x); p.y = psplit(a1.y); *(uint2*)(brow + 1 * 128 + c) = p;
    p.x = psplit(a2.x); p.y = psplit(a2.y); *(uint2*)(brow + 2 * 128 + c) = p;
    p.x = psplit(a3.x); p.y = psplit(a3.y); *(uint2*)(brow + 3 * 128 + c) = p;
    p.x = psplit(yx);   p.y = psplit(yy);   *(uint2*)(brow + 512 + c) = p;
}

// ---------------------------------------------------------------------------
// fused residual add + per-type BN stats
__global__ __launch_bounds__(256) void k_add_stats(float* __restrict__ h, const float* __restrict__ tc,
                                                   const int* __restrict__ typeStart, float* __restrict__ ssum,
                                                   float* __restrict__ ssq, int n) {
    __shared__ float red[256 * 17];
    const int tid = threadIdx.x;
    const int c = tid & 31;
    const int rs = tid >> 5;
    const int c0 = typeStart[1];
    const int i0 = blockIdx.x * 256;
    const int i1 = min(n, i0 + 256);
    v4f s0 = 0.f, q0 = 0.f, s1 = 0.f, q1 = 0.f;
    for (int i = i0 + rs; i < i1; i += 8) {
        v4f a = *(const v4f*)(h + (size_t)i * CC + 4 * c);
        a += *(const v4f*)(tc + (size_t)i * CC + 4 * c);
        *(v4f*)(h + (size_t)i * CC + 4 * c) = a;
        if (i < c0) { s0 += a; q0 += a * a; }
        else        { s1 += a; q1 += a * a; }
    }
#pragma unroll
    for (int j = 0; j < 4; ++j) {
        red[tid * 17 + j] = s0[j];
        red[tid * 17 + 4 + j] = q0[j];
        red[tid * 17 + 8 + j] = s1[j];
        red[tid * 17 + 12 + j] = q1[j];
    }
    __syncthreads();
    for (int o = tid; o < 512; o += 256) {
        const int col = o & 127, m = (o >> 7) & 1, t = (o >> 8) & 1;
        const int reg = t * 8 + m * 4 + (col & 3);
        float v = 0.f;
#pragma unroll
        for (int r = 0; r < 8; ++r) v += red[((col >> 2) + 32 * r) * 17 + reg];
        atomicAdd((m ? ssq : ssum) + t * CC + col, v);
    }
}

// ---------------------------------------------------------------------------
// MFMA GEMM: Y[r] (=/+=) srcact(X[r]) @ Wbf[t or 0] + B, split-A bf16 (hi+lo),
// W plain bf16 prepacked [K/8][OUTW][8].  128x128 block tile, 4 waves 2x2.
// PRESPLIT: X is packed hi/lo uint plane (chunk-local rows). BNIN: scale/shift+leaky.
template <int K, int OUTW, bool TYPED, bool WHET, bool PRESPLIT, bool BNIN,
          bool ACC, bool BHET, bool STATS>
__global__ __launch_bounds__(256) void k_mf(
    const float* __restrict__ Xf, const uint* __restrict__ Xp,
    const ushort* __restrict__ Wp, const float* __restrict__ Bb,
    const float* __restrict__ scale, const float* __restrict__ shift,
    const int* __restrict__ typeStart, float* __restrict__ Y,
    float* __restrict__ ssum, float* __restrict__ ssq,
    int rbeg_u, int rend_u) {
    __shared__ ushort AsH[128][40];
    __shared__ ushort AsL[128][40];
    __shared__ ushort Ws[4][128][8];
    __shared__ float csh[BNIN ? K : 1];
    __shared__ float cfh[BNIN ? K : 1];

    const int tid = threadIdx.x;
    const int lane = tid & 63;
    const int wid = tid >> 6;
    const int woffm = (wid >> 1) * 64, woffn = (wid & 1) * 64;

    int t = 0, rbeg = rbeg_u, rend = rend_u;
    if constexpr (TYPED) { t = blockIdx.y; rbeg = typeStart[t]; rend = typeStart[t + 1]; }
    const int r0 = rbeg + blockIdx.x * 128;
    if (r0 >= rend) return;
    const int zoff = blockIdx.z * 128;

    if constexpr (BNIN) {
        for (int k = tid; k < K; k += 256) { csh[k] = scale[t * K + k]; cfh[k] = shift[t * K + k]; }
    }
    __syncthreads();

    const int srow = tid >> 1, scg = (tid & 1) * 16;
    const int sgr = r0 + srow;
    const bool svalid = sgr < rend;
    const int wcp = tid & 63;

    v4f acc[4][4];
#pragma unroll
    for (int mt = 0; mt < 4; ++mt)
#pragma unroll
        for (int nt = 0; nt < 4; ++nt) acc[mt][nt] = (v4f){0.f, 0.f, 0.f, 0.f};

    const size_t wmat = (size_t)(WHET ? t : 0) * K * OUTW;

    for (int kt = 0; kt < K / 32; ++kt) {
        const int k0 = kt * 32;
        // ---- global loads (regs) ----
        ushort hA[16], lA[16];
        if constexpr (PRESPLIT) {
            const uint* xs = Xp + (size_t)(sgr - rbeg) * K + k0 + scg;
#pragma unroll
            for (int q = 0; q < 4; ++q) {
                uint4 u = svalid ? *(const uint4*)(xs + q * 4) : make_uint4(0, 0, 0, 0);
                hA[q * 4 + 0] = (ushort)(u.x >> 16); lA[q * 4 + 0] = (ushort)(u.x & 0xffff);
                hA[q * 4 + 1] = (ushort)(u.y >> 16); lA[q * 4 + 1] = (ushort)(u.y & 0xffff);
                hA[q * 4 + 2] = (ushort)(u.z >> 16); lA[q * 4 + 2] = (ushort)(u.z & 0xffff);
                hA[q * 4 + 3] = (ushort)(u.w >> 16); lA[q * 4 + 3] = (ushort)(u.w & 0xffff);
            }
        } else {
            const float* xs = Xf + (size_t)sgr * K + k0 + scg;
#pragma unroll
            for (int q = 0; q < 4; ++q) {
                v4f a = svalid ? *(const v4f*)(xs + q * 4) : (v4f)0.f;
#pragma unroll
                for (int j = 0; j < 4; ++j) {
                    float vv = a[j];
                    if constexpr (BNIN) {
                        const int k = k0 + scg + q * 4 + j;
                        vv = fmaf(vv, csh[k], cfh[k]);
                        vv = fmaxf(vv, 0.01f * vv);
                    }
                    const ushort hi = f2bf(vv);
                    hA[q * 4 + j] = hi;
                    lA[q * 4 + j] = f2bf(vv - bf2f(hi));
                }
            }
        }
        const ushort* wsrc = Wp + wmat + ((size_t)(k0 / 8 + wid) * OUTW + zoff) * 8 + (size_t)wcp * 16;
        const uint4 w0 = *(const uint4*)wsrc;
        const uint4 w1 = *(const uint4*)(wsrc + 8);

        __syncthreads();
        // ---- LDS writes ----
#pragma unroll
        for (int q = 0; q < 4; ++q) {
            *(ushort4*)&AsH[srow][scg + q * 4] =
                make_ushort4(hA[q * 4], hA[q * 4 + 1], hA[q * 4 + 2], hA[q * 4 + 3]);
            *(ushort4*)&AsL[srow][scg + q * 4] =
                make_ushort4(lA[q * 4], lA[q * 4 + 1], lA[q * 4 + 2], lA[q * 4 + 3]);
        }
        *(uint4*)&Ws[wid][swc(wcp * 2)][0] = w0;
        *(uint4*)&Ws[wid][swc(wcp * 2 + 1)][0] = w1;
        __syncthreads();

        // ---- fragments + MFMA ----
        const int afr = lane & 15;
        const int akg = (lane >> 4) * 8;
        bf16x8 aH[4], aL[4], wf[4];
#pragma unroll
        for (int mt = 0; mt < 4; ++mt) {
            aH[mt] = *(const bf16x8*)&AsH[woffm + mt * 16 + afr][akg];
            aL[mt] = *(const bf16x8*)&AsL[woffm + mt * 16 + afr][akg];
        }
#pragma unroll
        for (int nt = 0; nt < 4; ++nt)
            wf[nt] = *(const bf16x8*)&Ws[lane >> 4][swc(woffn + nt * 16 + afr)][0];
#pragma unroll
        for (int mt = 0; mt < 4; ++mt)
#pragma unroll
            for (int nt = 0; nt < 4; ++nt) {
                acc[mt][nt] = __builtin_amdgcn_mfma_f32_16x16x32_bf16(aH[mt], wf[nt], acc[mt][nt], 0, 0, 0);
                acc[mt][nt] = __builtin_amdgcn_mfma_f32_16x16x32_bf16(aL[mt], wf[nt], acc[mt][nt], 0, 0, 0);
            }
    }

    // ---- epilogue ----
    const float* BbT = Bb + (BHET ? (size_t)t * OUTW : 0);
    float bv[4];
#pragma unroll
    for (int nt = 0; nt < 4; ++nt) bv[nt] = BbT[zoff + woffn + nt * 16 + (lane & 15)];
    float cs[4] = {0.f, 0.f, 0.f, 0.f}, cq[4] = {0.f, 0.f, 0.f, 0.f};
#pragma unroll
    for (int mt = 0; mt < 4; ++mt) {
        const int grow = r0 + woffm + mt * 16 + (lane >> 4) * 4;
#pragma unroll
        for (int nt = 0; nt < 4; ++nt) {
            const int gcol = zoff + woffn + nt * 16 + (lane & 15);
#pragma unroll
            for (int rg = 0; rg < 4; ++rg) {
                const int gr = grow + rg;
                if (gr < rend) {
                    float v = acc[mt][nt][rg] + bv[nt];
                    float* yp = Y + (size_t)gr * OUTW + gcol;
                    if constexpr (ACC) v += *yp;
                    *yp = v;
                    if constexpr (STATS) { cs[nt] += v; cq[nt] += v * v; }
                }
            }
        }
    }
    if constexpr (STATS) {
#pragma unroll
        for (int nt = 0; nt < 4; ++nt) {
            float s = cs[nt], q = cq[nt];
            s += __shfl_xor(s, 16); q += __shfl_xor(q, 16);
            s += __shfl_xor(s, 32); q += __shfl_xor(q, 32);
            if (lane < 16) {
                atomicAdd(&ssum[t * OUTW + zoff + woffn + nt * 16 + lane], s);
                atomicAdd(&ssq[t * OUTW + zoff + woffn + nt * 16 + lane], q);
            }
        }
    }
}

// ---------------------------------------------------------------------------
// fp32 tiled GEMM (small K / small MOUT paths only)
template <int K, int MOUT, bool TYPED, bool GIN, bool SCOUT, bool WHET,
          bool ACC, bool BIAS, bool BNIN, bool STATS>
__global__ __launch_bounds__(256) void k_gemm(
    const float* __restrict__ X, const int* __restrict__ perm,
    const int* __restrict__ typeStart, const float* __restrict__ W,
    const float* __restrict__ B, const float* __restrict__ scale,
    const float* __restrict__ shift, float* __restrict__ Y,
    float* __restrict__ ssum, float* __restrict__ ssq, int n) {
    constexpr int BK = 16;
    constexpr int BM = 64;
    constexpr int TX = (MOUT >= 64) ? 16 : MOUT;
    constexpr int TY = 256 / TX;
    constexpr int VN = BM / TY;
    constexpr int VU = MOUT / TX;
    constexpr int NT = K / BK;
    constexpr int WQ = BK * MOUT / 4;
    constexpr int WR = (WQ + 255) / 256;

    __shared__ float As[BK][BM];
    __shared__ float Wsh[BK][MOUT];
    __shared__ float csh[BNIN ? K : 1];
    __shared__ float cfh[BNIN ? K : 1];
    __shared__ float lsum[STATS ? MOUT : 1];
    __shared__ float lsq[STATS ? MOUT : 1];

    const int tid = threadIdx.x;
    const int tx = tid % TX, ty = tid / TX;

    int t = 0, rbeg = 0, rend = n;
    if constexpr (TYPED) {
        t = blockIdx.y;
        rbeg = typeStart[t];
        rend = typeStart[t + 1];
    }
    const int r0 = rbeg + blockIdx.x * BM;
    if (r0 >= rend) return;

    const float* Wp = W + (WHET ? (size_t)t * K * MOUT : 0);

    if constexpr (BNIN) {
        for (int k = tid; k < K; k += 256) {
            csh[k] = scale[t * K + k];
            cfh[k] = shift[t * K + k];
        }
    }
    if constexpr (STATS) {
        for (int k = tid; k < MOUT; k += 256) { lsum[k] = 0.f; lsq[k] = 0.f; }
    }
    __syncthreads();

    const int srow = tid >> 2, skq = tid & 3;
    const int sgi = r0 + srow;
    const bool svalid = sgi < rend;
    const int sri = svalid ? (GIN ? perm[sgi] : sgi) : 0;
    const float* xrow = X + (size_t)sri * K;

    float acc[VN][VU];
#pragma unroll
    for (int v = 0; v < VN; ++v)
#pragma unroll
        for (int u = 0; u < VU; ++u) acc[v][u] = 0.f;

    for (int kt = 0; kt < NT; ++kt) {
        const int k0 = kt * BK;
        v4f a4 = 0.f;
        if (svalid) a4 = *(const v4f*)(xrow + k0 + skq * 4);
        if constexpr (BNIN) {
#pragma unroll
            for (int j = 0; j < 4; ++j) {
                const int k = k0 + skq * 4 + j;
                const float vv = fmaf(a4[j], csh[k], cfh[k]);
                a4[j] = fmaxf(vv, 0.01f * vv);
            }
        }
        v4f wreg[WR];
#pragma unroll
        for (int q = 0; q < WR; ++q) {
            const int idx = tid + q * 256;
            if (idx < WQ) wreg[q] = *(const v4f*)(Wp + (size_t)k0 * MOUT + (size_t)idx * 4);
        }
        __syncthreads();
#pragma unroll
        for (int j = 0; j < 4; ++j) As[skq * 4 + j][srow] = a4[j];
#pragma unroll
        for (int q = 0; q < WR; ++q) {
            const int idx = tid + q * 256;
            if (idx < WQ) *(v4f*)(&Wsh[0][0] + (size_t)idx * 4) = wreg[q];
        }
        __syncthreads();

#pragma unroll
        for (int kk = 0; kk < BK; ++kk) {
            float a[VN];
            if constexpr (TX == 16) {
                const v4f av = *(const v4f*)&As[kk][ty * 4];
#pragma unroll
                for (int j = 0; j < 4; ++j) a[j] = av[j];
            } else {
                a[0] = As[kk][ty];
            }
            if constexpr (MOUT >= 64) {
#pragma unroll
                for (int uq = 0; uq < VU / 4; ++uq) {
                    const v4f wv = *(const v4f*)&Wsh[kk][uq * 64 + tx * 4];
#pragma unroll
                    for (int v = 0; v < VN; ++v)
#pragma unroll
                        for (int j = 0; j < 4; ++j) acc[v][uq * 4 + j] += a[v] * wv[j];
                }
            } else {
                const float wv = Wsh[kk][tx];
#pragma unroll
                for (int v = 0; v < VN; ++v) acc[v][0] += a[v] * wv;
            }
        }
        __syncthreads();
    }

    const float* Bp = B + (WHET ? (size_t)t * MOUT : 0);
    float csum[STATS ? VU : 1], csq[STATS ? VU : 1];
    if constexpr (STATS) {
#pragma unroll
        for (int u = 0; u < VU; ++u) { csum[u] = 0.f; csq[u] = 0.f; }
    }
#pragma unroll
    for (int v = 0; v < VN; ++v) {
        const int gi = r0 + ty * VN + v;
        if (gi >= rend) continue;
        float* yp = Y + (size_t)(SCOUT ? perm[gi] : gi) * MOUT;
        if constexpr (MOUT >= 64) {
#pragma unroll
            for (int uq = 0; uq < VU / 4; ++uq) {
                const int cb = uq * 64 + tx * 4;
                v4f o;
#pragma unroll
                for (int j = 0; j < 4; ++j) o[j] = acc[v][uq * 4 + j];
                if (BIAS) o += *(const v4f*)(Bp + cb);
                if (ACC) o += *(const v4f*)(yp + cb);
                *(v4f*)(yp + cb) = o;
                if constexpr (STATS) {
#pragma unroll
                    for (int j = 0; j < 4; ++j) {
                        csum[uq * 4 + j] += o[j];
                        csq[uq * 4 + j] += o[j] * o[j];
                    }
                }
            }
        } else {
            float o = acc[v][0];
            if (BIAS) o += Bp[tx];
            if (ACC) o += yp[tx];
            yp[tx] = o;
        }
    }
    if constexpr (STATS) {
#pragma unroll
        for (int u = 0; u < VU; ++u) {
            const int col = (u >> 2) * 64 + tx * 4 + (u & 3);
            atomicAdd(&lsum[col], csum[u]);
            atomicAdd(&lsq[col], csq[u]);
        }
        __syncthreads();
        for (int col = tid; col < MOUT; col += 256) {
            atomicAdd(&ssum[t * MOUT + col], lsum[col]);
            atomicAdd(&ssq[t * MOUT + col], lsq[col]);
        }
    }
}

// ---------------------------------------------------------------------------
extern "C" void kernel_launch(void* const* d_in, const int* in_sizes, int n_in,
                              void* d_out, int out_size, void* d_ws, size_t ws_size,
                              hipStream_t stream) {
    const float* x = (const float*)d_in[0];
    const int* ei = (const int*)d_in[1];
    const int* nt = (const int*)d_in[2];
    const int* et = (const int*)d_in[3];
    const float* ri_w0 = (const float*)d_in[4];
    const float* ri_b0 = (const float*)d_in[5];
    const float* ri_g0 = (const float*)d_in[6];
    const float* ri_be0 = (const float*)d_in[7];
    const float* ri_w1 = (const float*)d_in[8];
    const float* ri_b1 = (const float*)d_in[9];
    const float* cn_g = (const float*)d_in[10];
    const float* cn_b = (const float*)d_in[11];
    const float* rg_w = (const float*)d_in[12];
    const float* rg_root = (const float*)d_in[13];
    const float* rg_bias = (const float*)d_in[14];
    const float* mn_g = (const float*)d_in[15];
    const float* mn_b = (const float*)d_in[16];
    const float* mw0 = (const float*)d_in[17];
    const float* mb0 = (const float*)d_in[18];
    const float* mg0 = (const float*)d_in[19];
    const float* mbe0 = (const float*)d_in[20];
    const float* mw1 = (const float*)d_in[21];
    const float* mb1 = (const float*)d_in[22];
    const float* ro_w0 = (const float*)d_in[23];
    const float* ro_b0 = (const float*)d_in[24];
    const float* ro_g0 = (const float*)d_in[25];
    const float* ro_be0 = (const float*)d_in[26];
    const float* ro_w1 = (const float*)d_in[27];
    const float* ro_b1 = (const float*)d_in[28];

    const int n = in_sizes[2];
    const int nE = in_sizes[3];
    const int* srcv = ei;
    const int* dstv = ei + nE;

    const int CHK = (((n + 3) / 4) + 127) & ~127;
    const size_t bufBytes = (size_t)CHK * 640 * sizeof(uint);
    const size_t a256Bytes = (size_t)n * HH * sizeof(float);
    const size_t tconvBytes = (size_t)n * CC * sizeof(float);
    const size_t regionABytes = (bufBytes + tconvBytes > a256Bytes) ? (bufBytes + tconvBytes) : a256Bytes;

    char* w = (char*)d_ws;
    size_t off = 0;
    auto alloc = [&](size_t bytes) -> char* {
        char* p = w + off;
        off = (off + bytes + 255) & ~(size_t)255;
        return p;
    };
    char* regionA = alloc(regionABytes);
    float* h = (float*)alloc((size_t)n * CC * sizeof(float));
    int* csr = (int*)alloc((size_t)nE * sizeof(int));
    int* rowp2 = (int*)alloc(((size_t)4 * n + 1) * sizeof(int));
    int* perm = (int*)alloc((size_t)n * sizeof(int));
    int* inv = (int*)alloc((size_t)n * sizeof(int));
    int* pscan = (int*)alloc((size_t)(n + 1) * sizeof(int));
    int* part = (int*)alloc(1032 * sizeof(int));
    int* typeStart = (int*)alloc(64);
    float* statbuf = (float*)alloc(10 * 1024 * sizeof(float));
    float* scale = (float*)alloc(512 * sizeof(float));
    float* shift = (float*)alloc(512 * sizeof(float));
    ushort* pw_ri1 = (ushort*)alloc(65536 * 2);
    ushort* pw_mw0 = (ushort*)alloc(131072 * 2);
    ushort* pw_mw1 = (ushort*)alloc(131072 * 2);
    ushort* pw_ro0 = (ushort*)alloc(65536 * 2);
    ushort* pw_conv = (ushort*)alloc(163840 * 2);
    if (ws_size < off) return;

    float* A256 = (float*)regionA;
    uint* buf = (uint*)regionA;
    float* tconv = (float*)(regionA + bufBytes);
    int* cur2 = (int*)regionA;  // setup phase only
    float* out = (float*)d_out;

    auto SS = [&](int slot) { return statbuf + (size_t)slot * 1024; };
    auto SQ = [&](int slot) { return statbuf + (size_t)slot * 1024 + 512; };

    const int gE = (nE + 255) / 256;
    const int gN = (n + 255) / 256;
    const int nb = (n + 1023) / 1024;
    const int m4 = 4 * n;
    const int nb2 = (m4 + 1023) / 1024;
    const int gmx = (n + 127) / 128;
    const dim3 g64((n + 63) / 64, 2);

    // ---- weight packing (bf16 fragment layout) ----
    k_pack<<<128, 256, 0, stream>>>(ri_w1, pw_ri1, 256, 128, 2LL * 256 * 128);
    k_pack<<<256, 256, 0, stream>>>(mw0, pw_mw0, 128, 256, 4LL * 128 * 256);
    k_pack<<<256, 256, 0, stream>>>(mw1, pw_mw1, 256, 128, 4LL * 256 * 128);
    k_pack<<<128, 256, 0, stream>>>(ro_w0, pw_ro0, 128, 256, 2LL * 128 * 256);
    for (int l = 0; l < LL; ++l)
        k_pack_conv<<<320, 256, 0, stream>>>(rg_w + (size_t)l * RR * CC * CC,
                                             rg_root + (size_t)l * CC * CC,
                                             pw_conv + (size_t)l * 640 * 128);

    // ---- setup: type partition + (dst,rel) CSR ----
    hipMemsetAsync(statbuf, 0, 10 * 1024 * sizeof(float), stream);
    k_scan1<<<nb, 1024, 0, stream>>>(nt, pscan, part, n);
    k_scan2<<<1, 1024, 0, stream>>>(part, nb);
    k_scan3<<<(n + 1024) / 1024, 1024, 0, stream>>>(pscan, part, n, nb);
    k_meta<<<1, 1, 0, stream>>>(pscan, typeStart, n);
    k_build_perm<<<gN, 256, 0, stream>>>(nt, pscan, typeStart, perm, inv, n);
    hipMemsetAsync(rowp2, 0, ((size_t)m4 + 1) * sizeof(int), stream);
    k_deg2<<<gE, 256, 0, stream>>>(dstv, et, inv, rowp2, nE);
    k_scan1<<<nb2, 1024, 0, stream>>>(rowp2, rowp2, part, m4);
    k_scan2<<<1, 1024, 0, stream>>>(part, nb2);
    k_scan3<<<(m4 + 1024) / 1024, 1024, 0, stream>>>(rowp2, part, m4, nb2);
    hipMemcpyAsync(cur2, rowp2, (size_t)m4 * sizeof(int), hipMemcpyDeviceToDevice, stream);
    k_fill2<<<gE, 256, 0, stream>>>(srcv, dstv, et, inv, cur2, csr, nE);

    // ---- readin ----
    k_gemm<DIN, HH, true, true, false, true, false, true, false, true><<<g64, 256, 0, stream>>>(
        x, perm, typeStart, ri_w0, ri_b0, nullptr, nullptr, A256, SS(0), SQ(0), n);
    k_coef<<<1, 512, 0, stream>>>(SS(0), SQ(0), typeStart, ri_g0, ri_be0, scale, shift, HH);
    k_mf<256, 128, true, true, false, true, false, true, true><<<dim3(gmx, 2, 1), 256, 0, stream>>>(
        A256, nullptr, pw_ri1, ri_b1, scale, shift, typeStart, h, SS(1), SQ(1), 0, n);

    // ---- RES+ layers ----
    for (int l = 0; l < LL; ++l) {
        const int s_cn = l ? 4 : 1, s_mn = l ? 5 : 2, s_mg = l ? 6 : 3, s_nx = l ? 7 : 4;
        k_coef<<<1, 512, 0, stream>>>(SS(s_cn), SQ(s_cn), typeStart,
                                      cn_g + (size_t)l * TT * CC, cn_b + (size_t)l * TT * CC,
                                      scale, shift, CC);
        for (int q0 = 0; q0 < n; q0 += CHK) {
            const int rows = min(CHK, n - q0);
            k_agg4<<<(rows + 3) / 4, 256, 0, stream>>>(h, rowp2, csr, scale, shift, typeStart,
                                                       buf, q0, q0 + rows);
            k_mf<640, 128, false, false, true, false, false, false, false>
                <<<dim3((rows + 127) / 128, 1, 1), 256, 0, stream>>>(
                    nullptr, buf, pw_conv + (size_t)l * 640 * 128, rg_bias + (size_t)l * CC,
                    nullptr, nullptr, typeStart, tconv, nullptr, nullptr, q0, q0 + rows);
        }
        k_add_stats<<<(n + 255) / 256, 256, 0, stream>>>(h, tconv, typeStart, SS(s_mn), SQ(s_mn), n);

        k_coef<<<1, 512, 0, stream>>>(SS(s_mn), SQ(s_mn), typeStart,
                                      mn_g + (size_t)l * TT * CC, mn_b + (size_t)l * TT * CC,
                                      scale, shift, CC);
        k_mf<128, 256, true, true, false, true, false, true, true><<<dim3(gmx, 2, 2), 256, 0, stream>>>(
            h, nullptr, pw_mw0 + (size_t)l * 2 * 128 * 256, mb0 + (size_t)l * TT * HH,
            scale, shift, typeStart, A256, SS(s_mg), SQ(s_mg), 0, n);
        k_coef<<<1, 512, 0, stream>>>(SS(s_mg), SQ(s_mg), typeStart,
                                      mg0 + (size_t)l * TT * HH, mbe0 + (size_t)l * TT * HH,
                                      scale, shift, HH);
        k_mf<256, 128, true, true, false, true, true, true, true><<<dim3(gmx, 2, 1), 256, 0, stream>>>(
            A256, nullptr, pw_mw1 + (size_t)l * 2 * 256 * 128, mb1 + (size_t)l * TT * CC,
            scale, shift, typeStart, h, SS(s_nx), SQ(s_nx), 0, n);
    }

    // ---- readout ----
    k_mf<128, 256, true, true, false, false, false, true, true><<<dim3(gmx, 2, 2), 256, 0, stream>>>(
        h, nullptr, pw_ro0, ro_b0, nullptr, nullptr, typeStart, A256, SS(8), SQ(8), 0, n);
    k_coef<<<1, 512, 0, stream>>>(SS(8), SQ(8), typeStart, ro_g0, ro_be0, scale, shift, HH);
    k_gemm<HH, DOUT, true, false, true, true, false, true, true, false><<<g64, 256, 0, stream>>>(
        A256, perm, typeStart, ro_w1, ro_b1, scale, shift, out, nullptr, nullptr, n);
}

// Round 5
// 839.301 us; speedup vs baseline: 10.4638x; 1.5018x over previous
//
#include <hip/hip_runtime.h>

#define TT 2
#define RR 4
#define LL 2
#define DIN 16
#define HH 256
#define CC 128
#define DOUT 4
#define EPS 1e-5f
#define NB 32   // stat buckets
#define NBG 16  // gram buckets

typedef float v4f __attribute__((ext_vector_type(4)));
typedef short bf16x8 __attribute__((ext_vector_type(8)));

__device__ __forceinline__ ushort f2bf(float x) {
    uint u = __float_as_uint(x);
    return (ushort)((u + 0x7fffu + ((u >> 16) & 1u)) >> 16);
}
__device__ __forceinline__ float bf2f(ushort h) { return __uint_as_float(((uint)h) << 16); }
__device__ __forceinline__ int swc(int c) { return c ^ ((c >> 3) & 7); }
__device__ __forceinline__ uint pack2(float x, float y) {
    return (uint)f2bf(x) | ((uint)f2bf(y) << 16);
}

// ---------------------------------------------------------------------------
// hierarchical exclusive scan
__global__ __launch_bounds__(1024) void k_scan1(const int* __restrict__ in, int* __restrict__ out,
                                                int* __restrict__ part, int n) {
    __shared__ int sm[1024];
    const int tid = threadIdx.x;
    const int i = blockIdx.x * 1024 + tid;
    const int v = (i < n) ? in[i] : 0;
    sm[tid] = v;
    __syncthreads();
    for (int off = 1; off < 1024; off <<= 1) {
        const int u = (tid >= off) ? sm[tid - off] : 0;
        __syncthreads();
        sm[tid] += u;
        __syncthreads();
    }
    if (i < n) out[i] = sm[tid] - v;
    if (tid == 1023) part[blockIdx.x] = sm[1023];
}

__global__ __launch_bounds__(1024) void k_scan2(int* __restrict__ part, int nb) {
    __shared__ int sm[1024];
    const int tid = threadIdx.x;
    const int v = (tid < nb) ? part[tid] : 0;
    sm[tid] = v;
    __syncthreads();
    for (int off = 1; off < 1024; off <<= 1) {
        const int u = (tid >= off) ? sm[tid - off] : 0;
        __syncthreads();
        sm[tid] += u;
        __syncthreads();
    }
    if (tid < nb) part[tid] = sm[tid] - v;
    if (tid == nb - 1) part[nb] = sm[tid];
}

__global__ __launch_bounds__(1024) void k_scan3(int* __restrict__ arr, const int* __restrict__ part,
                                                int n, int nb) {
    const int i = blockIdx.x * 1024 + threadIdx.x;
    if (i < n) arr[i] += part[i >> 10];
    else if (i == n) arr[n] = part[nb];
}

__global__ void k_meta(const int* __restrict__ pscan, int* __restrict__ typeStart, int n) {
    const int c1 = pscan[n];
    typeStart[0] = 0; typeStart[1] = n - c1; typeStart[2] = n;
}

__global__ __launch_bounds__(256) void k_build_perm(const int* __restrict__ nt, const int* __restrict__ pscan,
                                                    const int* __restrict__ typeStart, int* __restrict__ perm,
                                                    int* __restrict__ inv, int n) {
    const int i = blockIdx.x * 256 + threadIdx.x;
    if (i >= n) return;
    const int s1 = pscan[i];
    const int pos = nt[i] ? (typeStart[1] + s1) : (i - s1);
    perm[pos] = i;
    inv[i] = pos;
}

__global__ __launch_bounds__(256) void k_deg2(const int* __restrict__ dstv, const int* __restrict__ et,
                                              const int* __restrict__ inv, int* __restrict__ rowp2, int nE) {
    const int e = blockIdx.x * 256 + threadIdx.x;
    if (e < nE) atomicAdd(&rowp2[inv[dstv[e]] * 4 + et[e]], 1);
}

__global__ __launch_bounds__(256) void k_fill2(const int* __restrict__ srcv, const int* __restrict__ dstv,
                                               const int* __restrict__ et, const int* __restrict__ inv,
                                               int* __restrict__ cur, int* __restrict__ csr, int nE) {
    const int e = blockIdx.x * 256 + threadIdx.x;
    if (e < nE) {
        const int pos = atomicAdd(&cur[inv[dstv[e]] * 4 + et[e]], 1);
        csr[pos] = inv[srcv[e]];
    }
}

// ---------------------------------------------------------------------------
// weight packing: [nmat][K][N] f32 -> [mat][K/8][N][8] bf16
__global__ __launch_bounds__(256) void k_pack(const float* __restrict__ src, ushort* __restrict__ dst,
                                              int K, int N, long long total) {
    for (long long idx = (long long)blockIdx.x * 256 + threadIdx.x; idx < total;
         idx += (long long)gridDim.x * 256) {
        const long long kn = (long long)K * N;
        const int mat = (int)(idx / kn);
        const int rem = (int)(idx - mat * kn);
        const int k = rem / N, col = rem % N;
        dst[((size_t)mat * (K / 8) + (k >> 3)) * N * 8 + (size_t)col * 8 + (k & 7)] = f2bf(src[idx]);
    }
}

// conv stacked W: rows 0..511 = rg_w[r][kin][col], rows 512..639 = root[k][col]
__global__ __launch_bounds__(256) void k_pack_conv(const float* __restrict__ rgw, const float* __restrict__ root,
                                                   ushort* __restrict__ dst) {
    const int idx = blockIdx.x * 256 + threadIdx.x;
    if (idx >= 640 * 128) return;
    const int k = idx >> 7, col = idx & 127;
    const float v = (k < 512) ? rgw[(((k >> 7) * CC) + (k & 127)) * CC + col]
                              : root[(size_t)(k - 512) * CC + col];
    dst[((size_t)(k >> 3) * CC + col) * 8 + (k & 7)] = f2bf(v);
}

// ---------------------------------------------------------------------------
// bucketed stats -> scale/shift
__global__ __launch_bounds__(512) void k_coef(const float* __restrict__ stat, const int* __restrict__ typeStart,
                                              const float* __restrict__ g, const float* __restrict__ be,
                                              float* __restrict__ scale, float* __restrict__ shift, int F) {
    const int tid = threadIdx.x;
    if (tid >= TT * F) return;
    const int t = tid / F;
    float s = 0.f, q = 0.f;
    for (int b = 0; b < NB; ++b) {
        s += stat[(size_t)b * 1024 + tid];
        q += stat[(size_t)b * 1024 + 512 + tid];
    }
    const float cnt = fmaxf((float)(typeStart[t + 1] - typeStart[t]), 1.f);
    const float mean = s / cnt;
    const float var = q / cnt - mean * mean;
    const float sc = g[tid] * rsqrtf(var + EPS);
    scale[tid] = sc;
    shift[tid] = be[tid] - mean * sc;
}

// ---------------------------------------------------------------------------
// Gram matrix of x per type: gram[t][bucket][272] = {G[256], s[16]}
__global__ __launch_bounds__(256) void k_gram(const float* __restrict__ x, const int* __restrict__ perm,
                                              const int* __restrict__ typeStart, float* __restrict__ gram) {
    __shared__ float Xs[256][17];
    const int tid = threadIdx.x;
    const int t = blockIdx.y;
    const int rbeg = typeStart[t], rend = typeStart[t + 1];
    const int r0 = rbeg + blockIdx.x * 1024;
    if (r0 >= rend) return;
    const int i = tid >> 4, j = tid & 15;
    float acc = 0.f, sacc = 0.f;
    for (int rr = 0; rr < 4; ++rr) {
        const int gr = r0 + rr * 256 + tid;
        v4f x0 = 0.f, x1 = 0.f, x2 = 0.f, x3 = 0.f;
        if (gr < rend) {
            const float* xr = x + (size_t)perm[gr] * DIN;
            x0 = *(const v4f*)xr; x1 = *(const v4f*)(xr + 4);
            x2 = *(const v4f*)(xr + 8); x3 = *(const v4f*)(xr + 12);
        }
        __syncthreads();
#pragma unroll
        for (int e = 0; e < 4; ++e) { Xs[tid][e] = x0[e]; Xs[tid][4 + e] = x1[e];
                                      Xs[tid][8 + e] = x2[e]; Xs[tid][12 + e] = x3[e]; }
        __syncthreads();
        for (int r = 0; r < 256; ++r) acc += Xs[r][i] * Xs[r][j];
        if (tid < 16)
            for (int r = 0; r < 256; ++r) sacc += Xs[r][tid];
        __syncthreads();
    }
    float* gb = gram + ((size_t)t * NBG + (blockIdx.x & (NBG - 1))) * 272;
    atomicAdd(&gb[tid], acc);
    if (tid < 16) atomicAdd(&gb[256 + tid], sacc);
}

// analytic readin BN coef, folded into effective W0', b0'
__global__ __launch_bounds__(512) void k_ri_coef(const float* __restrict__ gram, const int* __restrict__ typeStart,
                                                 const float* __restrict__ ri_w0, const float* __restrict__ ri_b0,
                                                 const float* __restrict__ g, const float* __restrict__ be,
                                                 float* __restrict__ w0eff, float* __restrict__ b0eff) {
    __shared__ float G[2][272];
    const int tid = threadIdx.x;
    for (int idx = tid; idx < 2 * 272; idx += 512) {
        const int tt = idx / 272, k = idx % 272;
        float s = 0.f;
        for (int b = 0; b < NBG; ++b) s += gram[((size_t)tt * NBG + b) * 272 + k];
        G[tt][k] = s;
    }
    __syncthreads();
    const int t = tid >> 8, c = tid & 255;
    float wv[16];
#pragma unroll
    for (int k = 0; k < 16; ++k) wv[k] = ri_w0[((size_t)t * 16 + k) * HH + c];
    const float b = ri_b0[t * HH + c];
    const float cnt = fmaxf((float)(typeStart[t + 1] - typeStart[t]), 1.f);
    float sw = 0.f;
#pragma unroll
    for (int k = 0; k < 16; ++k) sw += G[t][256 + k] * wv[k];
    const float mean = (sw + cnt * b) / cnt;
    float e2 = 0.f;
#pragma unroll
    for (int i = 0; i < 16; ++i) {
        const float wi = wv[i];
#pragma unroll
        for (int j = 0; j < 16; ++j) e2 += wi * wv[j] * G[t][i * 16 + j];
    }
    e2 = (e2 + 2.f * b * sw + cnt * b * b) / cnt;
    const float var = e2 - mean * mean;
    const float sc = g[t * HH + c] * rsqrtf(var + EPS);
    const float sf = be[t * HH + c] - mean * sc;
    b0eff[t * HH + c] = b * sc + sf;
#pragma unroll
    for (int k = 0; k < 16; ++k) w0eff[((size_t)t * 16 + k) * HH + c] = wv[k] * sc;
}

// ---------------------------------------------------------------------------
// fused readin: h = act(x@W0'+b0') @ ri_w1 + ri_b1 ; writes h, h16, stats slot
__global__ __launch_bounds__(256) void k_readin(const float* __restrict__ x, const int* __restrict__ perm,
                                                const int* __restrict__ typeStart,
                                                const float* __restrict__ w0eff, const float* __restrict__ b0eff,
                                                const ushort* __restrict__ Wp, const float* __restrict__ b1,
                                                float* __restrict__ h, ushort* __restrict__ h16,
                                                float* __restrict__ stat) {
    __shared__ float Xs[128][17];
    __shared__ float W0s[16][256];
    __shared__ float b0s[256];
    __shared__ ushort As[128][40];
    __shared__ ushort Ws[4][128][8];

    const int tid = threadIdx.x;
    const int lane = tid & 63;
    const int wid = tid >> 6;
    const int woffm = (wid >> 1) * 64, woffn = (wid & 1) * 64;
    const int t = blockIdx.y;
    const int rbeg = typeStart[t], rend = typeStart[t + 1];
    const int r0 = rbeg + blockIdx.x * 128;
    if (r0 >= rend) return;

    for (int idx = tid; idx < 16 * 256; idx += 256) W0s[idx >> 8][idx & 255] = w0eff[(size_t)t * 4096 + idx];
    if (tid < 256) b0s[tid] = b0eff[t * 256 + tid];

    const int srow = tid >> 1, half = tid & 1;
    const int sgr = r0 + srow;
    const bool svalid = sgr < rend;
    {
        v4f x0 = 0.f, x1 = 0.f;
        if (svalid) {
            const float* xr = x + (size_t)perm[sgr] * DIN + half * 8;
            x0 = *(const v4f*)xr; x1 = *(const v4f*)(xr + 4);
        }
#pragma unroll
        for (int e = 0; e < 4; ++e) { Xs[srow][half * 8 + e] = x0[e]; Xs[srow][half * 8 + 4 + e] = x1[e]; }
    }
    __syncthreads();
    float xr[16];
#pragma unroll
    for (int k = 0; k < 16; ++k) xr[k] = Xs[srow][k];

    v4f acc[4][4];
#pragma unroll
    for (int mt = 0; mt < 4; ++mt)
#pragma unroll
        for (int nt = 0; nt < 4; ++nt) acc[mt][nt] = (v4f){0.f, 0.f, 0.f, 0.f};

    const size_t wmat = (size_t)t * 256 * 128;
    const int wcp = tid & 63;

    for (int kt = 0; kt < 8; ++kt) {
        const int k0 = kt * 32;
        ushort hA[16];
#pragma unroll
        for (int c2 = 0; c2 < 16; ++c2) {
            const int col = k0 + half * 16 + c2;
            float d = b0s[col];
#pragma unroll
            for (int k = 0; k < 16; ++k) d = fmaf(xr[k], W0s[k][col], d);
            d = fmaxf(d, 0.01f * d);
            hA[c2] = f2bf(d);
        }
        const ushort* wsrc = Wp + wmat + ((size_t)(k0 / 8 + wid) * 128) * 8 + (size_t)wcp * 16;
        const uint4 w0 = *(const uint4*)wsrc;
        const uint4 w1 = *(const uint4*)(wsrc + 8);
        __syncthreads();
        *(uint4*)&As[srow][half * 16] = *(uint4*)&hA[0];
        *(uint4*)&As[srow][half * 16 + 8] = *(uint4*)&hA[8];
        *(uint4*)&Ws[wid][swc(wcp * 2)][0] = w0;
        *(uint4*)&Ws[wid][swc(wcp * 2 + 1)][0] = w1;
        __syncthreads();
        const int afr = lane & 15;
        const int akg = (lane >> 4) * 8;
        bf16x8 aF[4], wf[4];
#pragma unroll
        for (int mt = 0; mt < 4; ++mt) aF[mt] = *(const bf16x8*)&As[woffm + mt * 16 + afr][akg];
#pragma unroll
        for (int nt = 0; nt < 4; ++nt) wf[nt] = *(const bf16x8*)&Ws[lane >> 4][swc(woffn + nt * 16 + afr)][0];
#pragma unroll
        for (int mt = 0; mt < 4; ++mt)
#pragma unroll
            for (int nt = 0; nt < 4; ++nt)
                acc[mt][nt] = __builtin_amdgcn_mfma_f32_16x16x32_bf16(aF[mt], wf[nt], acc[mt][nt], 0, 0, 0);
    }

    float bv[4];
#pragma unroll
    for (int nt = 0; nt < 4; ++nt) bv[nt] = b1[t * 128 + woffn + nt * 16 + (lane & 15)];
    float cs[4] = {0.f, 0.f, 0.f, 0.f}, cq[4] = {0.f, 0.f, 0.f, 0.f};
#pragma unroll
    for (int mt = 0; mt < 4; ++mt) {
        const int grow = r0 + woffm + mt * 16 + (lane >> 4) * 4;
#pragma unroll
        for (int nt = 0; nt < 4; ++nt) {
            const int gcol = woffn + nt * 16 + (lane & 15);
#pragma unroll
            for (int rg = 0; rg < 4; ++rg) {
                const int gr = grow + rg;
                if (gr < rend) {
                    const float v = acc[mt][nt][rg] + bv[nt];
                    const size_t o = (size_t)gr * 128 + gcol;
                    h[o] = v;
                    h16[o] = f2bf(v);
                    cs[nt] += v; cq[nt] += v * v;
                }
            }
        }
    }
    float* sb = stat + (size_t)(blockIdx.x & (NB - 1)) * 1024;
#pragma unroll
    for (int nt = 0; nt < 4; ++nt) {
        float s = cs[nt], q = cq[nt];
        s += __shfl_xor(s, 16); q += __shfl_xor(q, 16);
        s += __shfl_xor(s, 32); q += __shfl_xor(q, 32);
        if (lane < 16) {
            const int col = t * 128 + woffn + nt * 16 + lane;
            atomicAdd(&sb[col], s);
            atomicAdd(&sb[512 + col], q);
        }
    }
}

// ---------------------------------------------------------------------------
// fused 4-relation aggregation + own-node BN from bf16 h-shadow -> bf16 buf
__global__ __launch_bounds__(256) void k_agg4(const ushort* __restrict__ h16, const int* __restrict__ rowp2,
                                              const int* __restrict__ csr, const float* __restrict__ scale,
                                              const float* __restrict__ shift, const int* __restrict__ typeStart,
                                              ushort* __restrict__ buf, int q0, int q1) {
    const int wid = threadIdx.x >> 6, lane = threadIdx.x & 63;
    const int i = q0 + blockIdx.x * 4 + wid;
    if (i >= q1) return;
    const int c = 2 * lane;
    const int c0 = typeStart[1];
    const float2 sa0 = *(const float2*)(scale + c);
    const float2 sb0 = *(const float2*)(shift + c);
    const float2 sa1 = *(const float2*)(scale + CC + c);
    const float2 sb1 = *(const float2*)(shift + CC + c);
    const uint* h32 = (const uint*)h16;
    float2 a0 = {0.f, 0.f}, a1 = {0.f, 0.f}, a2 = {0.f, 0.f}, a3 = {0.f, 0.f};
    const int e0 = rowp2[4 * i], b1 = rowp2[4 * i + 1], b2 = rowp2[4 * i + 2],
              b3 = rowp2[4 * i + 3], e1 = rowp2[4 * i + 4];
    for (int e = e0; e < e1; e += 64) {
        const int cnt = min(64, e1 - e);
        int pk = (lane < cnt) ? csr[e + lane] : 0;
        for (int j = 0; j < cnt; ++j) {
            const int s = __shfl(pk, j);
            const int idx = e + j;
            const bool tb = s >= c0;
            const uint u = h32[(size_t)s * 64 + lane];
            float vx = fmaf(bf2f((ushort)(u & 0xffff)), tb ? sa1.x : sa0.x, tb ? sb1.x : sb0.x);
            float vy = fmaf(bf2f((ushort)(u >> 16)), tb ? sa1.y : sa0.y, tb ? sb1.y : sb0.y);
            vx = fmaxf(vx, 0.01f * vx);
            vy = fmaxf(vy, 0.01f * vy);
            if (idx < b1)      { a0.x += vx; a0.y += vy; }
            else if (idx < b2) { a1.x += vx; a1.y += vy; }
            else if (idx < b3) { a2.x += vx; a2.y += vy; }
            else               { a3.x += vx; a3.y += vy; }
        }
    }
    const bool td = i >= c0;
    const uint hu = h32[(size_t)i * 64 + lane];
    float yx = fmaf(bf2f((ushort)(hu & 0xffff)), td ? sa1.x : sa0.x, td ? sb1.x : sb0.x);
    float yy = fmaf(bf2f((ushort)(hu >> 16)), td ? sa1.y : sa0.y, td ? sb1.y : sb0.y);
    yx = fmaxf(yx, 0.01f * yx);
    yy = fmaxf(yy, 0.01f * yy);
    uint* brow = (uint*)buf + (size_t)(i - q0) * 320;
    brow[0 * 64 + lane] = pack2(a0.x, a0.y);
    brow[1 * 64 + lane] = pack2(a1.x, a1.y);
    brow[2 * 64 + lane] = pack2(a2.x, a2.y);
    brow[3 * 64 + lane] = pack2(a3.x, a3.y);
    brow[256 + lane] = pack2(yx, yy);
}

// ---------------------------------------------------------------------------
// fused residual add + per-type BN stats (chunked-conv fallback), updates h16
__global__ __launch_bounds__(256) void k_add_stats(float* __restrict__ h, ushort* __restrict__ h16,
                                                   const float* __restrict__ tc,
                                                   const int* __restrict__ typeStart, float* __restrict__ stat,
                                                   int n) {
    __shared__ float red[256 * 17];
    const int tid = threadIdx.x;
    const int c = tid & 31;
    const int rs = tid >> 5;
    const int c0 = typeStart[1];
    const int i0 = blockIdx.x * 256;
    const int i1 = min(n, i0 + 256);
    v4f s0 = 0.f, q0 = 0.f, s1 = 0.f, q1 = 0.f;
    for (int i = i0 + rs; i < i1; i += 8) {
        v4f a = *(const v4f*)(h + (size_t)i * CC + 4 * c);
        a += *(const v4f*)(tc + (size_t)i * CC + 4 * c);
        *(v4f*)(h + (size_t)i * CC + 4 * c) = a;
        ushort4 hh = make_ushort4(f2bf(a[0]), f2bf(a[1]), f2bf(a[2]), f2bf(a[3]));
        *(ushort4*)(h16 + (size_t)i * CC + 4 * c) = hh;
        if (i < c0) { s0 += a; q0 += a * a; }
        else        { s1 += a; q1 += a * a; }
    }
#pragma unroll
    for (int j = 0; j < 4; ++j) {
        red[tid * 17 + j] = s0[j];
        red[tid * 17 + 4 + j] = q0[j];
        red[tid * 17 + 8 + j] = s1[j];
        red[tid * 17 + 12 + j] = q1[j];
    }
    __syncthreads();
    float* sb = stat + (size_t)(blockIdx.x & (NB - 1)) * 1024;
    for (int o = tid; o < 512; o += 256) {
        const int col = o & 127, m = (o >> 7) & 1, t = (o >> 8) & 1;
        const int reg = t * 8 + m * 4 + (col & 3);
        float v = 0.f;
#pragma unroll
        for (int r = 0; r < 8; ++r) v += red[((col >> 2) + 32 * r) * 17 + reg];
        atomicAdd(&sb[(m ? 512 : 0) + t * CC + col], v);
    }
}

// ---------------------------------------------------------------------------
// MFMA GEMM (bf16-hi only).
// XBF: X is bf16 (rows offset by rbase). BNIN: scale/shift+leaky on input.
// OUTMODE 0: Y=f32 store; 1: Y16=bf16 store; 2: h-accumulate (Y+=, Y16=bf16(h)).
// STATS: bucketed; per-type via TYPED t, else per-element (gr<c0).
template <int K, int OUTW, bool TYPED, bool WHET, bool XBF, bool BNIN, bool BHET, bool STATS, int OUTMODE>
__global__ __launch_bounds__(256) void k_mf(
    const float* __restrict__ Xf, const ushort* __restrict__ Xb,
    const ushort* __restrict__ Wp, const float* __restrict__ Bb,
    const float* __restrict__ scale, const float* __restrict__ shift,
    const int* __restrict__ typeStart, float* __restrict__ Y,
    ushort* __restrict__ Y16, float* __restrict__ stat,
    int rbase, int rbeg_u, int rend_u) {
    __shared__ ushort As[128][40];
    __shared__ ushort Ws[4][128][8];
    __shared__ float csh[BNIN ? K : 1];
    __shared__ float cfh[BNIN ? K : 1];

    const int tid = threadIdx.x;
    const int lane = tid & 63;
    const int wid = tid >> 6;
    const int woffm = (wid >> 1) * 64, woffn = (wid & 1) * 64;

    int t = 0, rbeg = rbeg_u, rend = rend_u;
    if constexpr (TYPED) { t = blockIdx.y; rbeg = typeStart[t]; rend = typeStart[t + 1]; }
    const int r0 = rbeg + blockIdx.x * 128;
    if (r0 >= rend) return;
    const int zoff = (OUTW == 256) ? blockIdx.z * 128 : 0;

    if constexpr (BNIN) {
        for (int k = tid; k < K; k += 256) { csh[k] = scale[t * K + k]; cfh[k] = shift[t * K + k]; }
        __syncthreads();
    }

    const int srow = tid >> 1, scg = (tid & 1) * 16;
    const int sgr = r0 + srow;
    const bool svalid = sgr < rend;
    const int wcp = tid & 63;

    v4f acc[4][4];
#pragma unroll
    for (int mt = 0; mt < 4; ++mt)
#pragma unroll
        for (int nt = 0; nt < 4; ++nt) acc[mt][nt] = (v4f){0.f, 0.f, 0.f, 0.f};

    const size_t wmat = (size_t)(WHET ? t : 0) * K * OUTW;

    for (int kt = 0; kt < K / 32; ++kt) {
        const int k0 = kt * 32;
        uint uu[8];
        if constexpr (XBF) {
            uint4 a0 = make_uint4(0, 0, 0, 0), a1 = make_uint4(0, 0, 0, 0);
            if (svalid) {
                const ushort* xs = Xb + (size_t)(sgr - rbase) * K + k0 + scg;
                a0 = *(const uint4*)xs;
                a1 = *(const uint4*)(xs + 8);
            }
            uu[0] = a0.x; uu[1] = a0.y; uu[2] = a0.z; uu[3] = a0.w;
            uu[4] = a1.x; uu[5] = a1.y; uu[6] = a1.z; uu[7] = a1.w;
            if constexpr (BNIN) {
#pragma unroll
                for (int e = 0; e < 8; ++e) {
                    const int k = k0 + scg + 2 * e;
                    float f0 = fmaf(bf2f((ushort)(uu[e] & 0xffff)), csh[k], cfh[k]);
                    float f1 = fmaf(bf2f((ushort)(uu[e] >> 16)), csh[k + 1], cfh[k + 1]);
                    f0 = fmaxf(f0, 0.01f * f0);
                    f1 = fmaxf(f1, 0.01f * f1);
                    uu[e] = pack2(f0, f1);
                }
            }
        } else {
            float fv[16];
            {
                v4f av0 = 0.f, av1 = 0.f, av2 = 0.f, av3 = 0.f;
                if (svalid) {
                    const float* xs = Xf + (size_t)sgr * K + k0 + scg;
                    av0 = *(const v4f*)xs; av1 = *(const v4f*)(xs + 4);
                    av2 = *(const v4f*)(xs + 8); av3 = *(const v4f*)(xs + 12);
                }
#pragma unroll
                for (int e = 0; e < 4; ++e) { fv[e] = av0[e]; fv[4 + e] = av1[e];
                                              fv[8 + e] = av2[e]; fv[12 + e] = av3[e]; }
            }
            if constexpr (BNIN) {
#pragma unroll
                for (int e = 0; e < 16; ++e) {
                    const int k = k0 + scg + e;
                    float vv = fmaf(fv[e], csh[k], cfh[k]);
                    fv[e] = fmaxf(vv, 0.01f * vv);
                }
            }
#pragma unroll
            for (int e = 0; e < 8; ++e) uu[e] = pack2(fv[2 * e], fv[2 * e + 1]);
        }
        const ushort* wsrc = Wp + wmat + ((size_t)(k0 / 8 + wid) * OUTW + zoff) * 8 + (size_t)wcp * 16;
        const uint4 w0 = *(const uint4*)wsrc;
        const uint4 w1 = *(const uint4*)(wsrc + 8);

        __syncthreads();
        *(uint4*)&As[srow][scg] = make_uint4(uu[0], uu[1], uu[2], uu[3]);
        *(uint4*)&As[srow][scg + 8] = make_uint4(uu[4], uu[5], uu[6], uu[7]);
        *(uint4*)&Ws[wid][swc(wcp * 2)][0] = w0;
        *(uint4*)&Ws[wid][swc(wcp * 2 + 1)][0] = w1;
        __syncthreads();

        const int afr = lane & 15;
        const int akg = (lane >> 4) * 8;
        bf16x8 aF[4], wf[4];
#pragma unroll
        for (int mt = 0; mt < 4; ++mt) aF[mt] = *(const bf16x8*)&As[woffm + mt * 16 + afr][akg];
#pragma unroll
        for (int nt = 0; nt < 4; ++nt) wf[nt] = *(const bf16x8*)&Ws[lane >> 4][swc(woffn + nt * 16 + afr)][0];
#pragma unroll
        for (int mt = 0; mt < 4; ++mt)
#pragma unroll
            for (int nt = 0; nt < 4; ++nt)
                acc[mt][nt] = __builtin_amdgcn_mfma_f32_16x16x32_bf16(aF[mt], wf[nt], acc[mt][nt], 0, 0, 0);
    }

    // ---- epilogue ----
    const float* BbT = Bb + (BHET ? (size_t)t * OUTW : 0);
    float bv[4];
#pragma unroll
    for (int nt = 0; nt < 4; ++nt) bv[nt] = BbT[zoff + woffn + nt * 16 + (lane & 15)];
    const int c0 = (STATS && !TYPED) ? typeStart[1] : 0;
    float cs0[4] = {0.f, 0.f, 0.f, 0.f}, cq0[4] = {0.f, 0.f, 0.f, 0.f};
    float cs1[4] = {0.f, 0.f, 0.f, 0.f}, cq1[4] = {0.f, 0.f, 0.f, 0.f};
#pragma unroll
    for (int mt = 0; mt < 4; ++mt) {
        const int grow = r0 + woffm + mt * 16 + (lane >> 4) * 4;
#pragma unroll
        for (int nt = 0; nt < 4; ++nt) {
            const int gcol = zoff + woffn + nt * 16 + (lane & 15);
#pragma unroll
            for (int rg = 0; rg < 4; ++rg) {
                const int gr = grow + rg;
                if (gr < rend) {
                    float v = acc[mt][nt][rg] + bv[nt];
                    const size_t o = (size_t)gr * OUTW + gcol;
                    if constexpr (OUTMODE == 0) Y[o] = v;
                    if constexpr (OUTMODE == 1) Y16[o] = f2bf(v);
                    if constexpr (OUTMODE == 2) {
                        const float hv = Y[o] + v;
                        Y[o] = hv;
                        Y16[o] = f2bf(hv);
                        v = hv;
                    }
                    if constexpr (STATS) {
                        if (TYPED || gr < c0) { cs0[nt] += v; cq0[nt] += v * v; }
                        else                  { cs1[nt] += v; cq1[nt] += v * v; }
                    }
                }
            }
        }
    }
    if constexpr (STATS) {
        float* sb = stat + (size_t)(blockIdx.x & (NB - 1)) * 1024;
#pragma unroll
        for (int nt = 0; nt < 4; ++nt) {
            float s = cs0[nt], q = cq0[nt];
            s += __shfl_xor(s, 16); q += __shfl_xor(q, 16);
            s += __shfl_xor(s, 32); q += __shfl_xor(q, 32);
            if (lane < 16) {
                const int col = t * OUTW + zoff + woffn + nt * 16 + lane;
                atomicAdd(&sb[col], s);
                atomicAdd(&sb[512 + col], q);
            }
            if constexpr (!TYPED) {
                float s1 = cs1[nt], q1 = cq1[nt];
                s1 += __shfl_xor(s1, 16); q1 += __shfl_xor(q1, 16);
                s1 += __shfl_xor(s1, 32); q1 += __shfl_xor(q1, 32);
                if (lane < 16) {
                    const int col = OUTW + zoff + woffn + nt * 16 + lane;
                    atomicAdd(&sb[col], s1);
                    atomicAdd(&sb[512 + col], q1);
                }
            }
        }
    }
}

// ---------------------------------------------------------------------------
// readout stage 2: out[perm[i]] = act(bn(A256b[i])) @ ro_w1[t] + ro_b1[t]
__global__ __launch_bounds__(256) void k_ro1(const ushort* __restrict__ A256b, const int* __restrict__ perm,
                                             const int* __restrict__ typeStart, const float* __restrict__ ro_w1,
                                             const float* __restrict__ ro_b1, const float* __restrict__ scale,
                                             const float* __restrict__ shift, float* __restrict__ out, int n) {
    __shared__ float W1s[2][256][4];
    __shared__ float scs[512];
    __shared__ float sfs[512];
    const int tid = threadIdx.x;
    for (int idx = tid; idx < 2048; idx += 256) {
        const int t = idx >> 10, rem = idx & 1023;
        W1s[t][rem >> 2][rem & 3] = ro_w1[idx];
    }
    for (int idx = tid; idx < 512; idx += 256) { scs[idx] = scale[idx]; sfs[idx] = shift[idx]; }
    __syncthreads();
    const int trow = tid >> 2, sub = tid & 3;
    const int gr = blockIdx.x * 64 + trow;
    if (gr >= n) return;
    const int c0 = typeStart[1];
    const int t = (gr >= c0) ? 1 : 0;
    v4f acc = 0.f;
    const ushort* ar = A256b + (size_t)gr * 256 + sub * 64;
#pragma unroll
    for (int q = 0; q < 8; ++q) {
        const uint4 u = *(const uint4*)(ar + q * 8);
        const uint uw[4] = {u.x, u.y, u.z, u.w};
#pragma unroll
        for (int e = 0; e < 4; ++e) {
#pragma unroll
            for (int hl = 0; hl < 2; ++hl) {
                const int col = sub * 64 + q * 8 + 2 * e + hl;
                const float v = bf2f((ushort)(hl ? (uw[e] >> 16) : (uw[e] & 0xffff)));
                float vv = fmaf(v, scs[t * 256 + col], sfs[t * 256 + col]);
                vv = fmaxf(vv, 0.01f * vv);
                acc += vv * *(const v4f*)&W1s[t][col][0];
            }
        }
    }
#pragma unroll
    for (int e = 0; e < 4; ++e) { acc[e] += __shfl_xor(acc[e], 1); acc[e] += __shfl_xor(acc[e], 2); }
    if (sub == 0) {
        acc += *(const v4f*)(ro_b1 + t * 4);
        *(v4f*)(out + (size_t)perm[gr] * 4) = acc;
    }
}

// ---------------------------------------------------------------------------
extern "C" void kernel_launch(void* const* d_in, const int* in_sizes, int n_in,
                              void* d_out, int out_size, void* d_ws, size_t ws_size,
                              hipStream_t stream) {
    const float* x = (const float*)d_in[0];
    const int* ei = (const int*)d_in[1];
    const int* nt = (const int*)d_in[2];
    const int* et = (const int*)d_in[3];
    const float* ri_w0 = (const float*)d_in[4];
    const float* ri_b0 = (const float*)d_in[5];
    const float* ri_g0 = (const float*)d_in[6];
    const float* ri_be0 = (const float*)d_in[7];
    const float* ri_w1 = (const float*)d_in[8];
    const float* ri_b1 = (const float*)d_in[9];
    const float* cn_g = (const float*)d_in[10];
    const float* cn_b = (const float*)d_in[11];
    const float* rg_w = (const float*)d_in[12];
    const float* rg_root = (const float*)d_in[13];
    const float* rg_bias = (const float*)d_in[14];
    const float* mn_g = (const float*)d_in[15];
    const float* mn_b = (const float*)d_in[16];
    const float* mw0 = (const float*)d_in[17];
    const float* mb0 = (const float*)d_in[18];
    const float* mg0 = (const float*)d_in[19];
    const float* mbe0 = (const float*)d_in[20];
    const float* mw1 = (const float*)d_in[21];
    const float* mb1 = (const float*)d_in[22];
    const float* ro_w0 = (const float*)d_in[23];
    const float* ro_b0 = (const float*)d_in[24];
    const float* ro_g0 = (const float*)d_in[25];
    const float* ro_be0 = (const float*)d_in[26];
    const float* ro_w1 = (const float*)d_in[27];
    const float* ro_b1 = (const float*)d_in[28];

    const int n = in_sizes[2];
    const int nE = in_sizes[3];
    const int* srcv = ei;
    const int* dstv = ei + nE;

    // ---- workspace ----
    char* w = (char*)d_ws;
    size_t off = 0;
    auto alloc = [&](size_t bytes) -> char* {
        char* p = w + off;
        off = (off + bytes + 255) & ~(size_t)255;
        return p;
    };
    float* h = (float*)alloc((size_t)n * CC * sizeof(float));
    ushort* h16 = (ushort*)alloc((size_t)n * CC * sizeof(ushort));
    int* csr = (int*)alloc((size_t)nE * sizeof(int));
    int* rowp2 = (int*)alloc(((size_t)4 * n + 1) * sizeof(int));
    int* perm = (int*)alloc((size_t)n * sizeof(int));
    int* inv = (int*)alloc((size_t)n * sizeof(int));
    int* pscan = (int*)alloc((size_t)(n + 1) * sizeof(int));
    int* part = (int*)alloc(2052 * sizeof(int));
    int* typeStart = (int*)alloc(64);
    float* statbuf = (float*)alloc((size_t)9 * NB * 1024 * sizeof(float));
    float* gram = (float*)alloc((size_t)2 * NBG * 272 * sizeof(float));
    float* scale = (float*)alloc(512 * sizeof(float));
    float* shift = (float*)alloc(512 * sizeof(float));
    float* w0eff = (float*)alloc((size_t)2 * 16 * 256 * sizeof(float));
    float* b0eff = (float*)alloc(512 * sizeof(float));
    ushort* pw_ri1 = (ushort*)alloc(65536 * 2);
    ushort* pw_mw0 = (ushort*)alloc(131072 * 2);
    ushort* pw_mw1 = (ushort*)alloc(131072 * 2);
    ushort* pw_ro0 = (ushort*)alloc(65536 * 2);
    ushort* pw_conv = (ushort*)alloc(163840 * 2);
    char* region2 = alloc((size_t)n * 512);  // A256 bf16 (MLP/readout)  OR  tconv f32 (chunked conv)
    if (ws_size < off) return;

    ushort* A256b = (ushort*)region2;
    float* tconv = (float*)region2;
    int* cur2 = (int*)region2;  // setup phase only
    float* out = (float*)d_out;

    // remaining workspace -> conv aggregation buffer (bf16 [rows][640])
    ushort* buf = (ushort*)(w + off);
    const size_t bufBytes = (ws_size > off) ? (ws_size - off) : 0;
    const long long chkcap = (long long)(bufBytes / 1280);
    if (chkcap < 1024) return;
    int nchunk, CHK;
    if (chkcap >= n) { nchunk = 1; CHK = n; }
    else { nchunk = (int)((n + chkcap - 1) / chkcap); CHK = (n + nchunk - 1) / nchunk; }

    auto SS = [&](int slot) { return statbuf + (size_t)slot * NB * 1024; };

    const int gE = (nE + 255) / 256;
    const int gN = (n + 255) / 256;
    const int nb = (n + 1023) / 1024;
    const int m4 = 4 * n;
    const int nb2 = (m4 + 1023) / 1024;
    const int gmx = (n + 127) / 128;

    // ---- weight packing ----
    k_pack<<<128, 256, 0, stream>>>(ri_w1, pw_ri1, 256, 128, 2LL * 256 * 128);
    k_pack<<<256, 256, 0, stream>>>(mw0, pw_mw0, 128, 256, 4LL * 128 * 256);
    k_pack<<<256, 256, 0, stream>>>(mw1, pw_mw1, 256, 128, 4LL * 256 * 128);
    k_pack<<<128, 256, 0, stream>>>(ro_w0, pw_ro0, 128, 256, 2LL * 128 * 256);
    for (int l = 0; l < LL; ++l)
        k_pack_conv<<<320, 256, 0, stream>>>(rg_w + (size_t)l * RR * CC * CC,
                                             rg_root + (size_t)l * CC * CC,
                                             pw_conv + (size_t)l * 640 * 128);

    // ---- setup ----
    hipMemsetAsync(statbuf, 0, (size_t)9 * NB * 1024 * sizeof(float), stream);
    hipMemsetAsync(gram, 0, (size_t)2 * NBG * 272 * sizeof(float), stream);
    k_scan1<<<nb, 1024, 0, stream>>>(nt, pscan, part, n);
    k_scan2<<<1, 1024, 0, stream>>>(part, nb);
    k_scan3<<<(n + 1024) / 1024, 1024, 0, stream>>>(pscan, part, n, nb);
    k_meta<<<1, 1, 0, stream>>>(pscan, typeStart, n);
    k_build_perm<<<gN, 256, 0, stream>>>(nt, pscan, typeStart, perm, inv, n);
    hipMemsetAsync(rowp2, 0, ((size_t)m4 + 1) * sizeof(int), stream);
    k_deg2<<<gE, 256, 0, stream>>>(dstv, et, inv, rowp2, nE);
    k_scan1<<<nb2, 1024, 0, stream>>>(rowp2, rowp2, part, m4);
    k_scan2<<<1, 1024, 0, stream>>>(part, nb2);
    k_scan3<<<(m4 + 1024) / 1024, 1024, 0, stream>>>(rowp2, part, m4, nb2);
    hipMemcpyAsync(cur2, rowp2, (size_t)m4 * sizeof(int), hipMemcpyDeviceToDevice, stream);
    k_fill2<<<gE, 256, 0, stream>>>(srcv, dstv, et, inv, cur2, csr, nE);

    // ---- readin (fused): gram -> analytic coef -> x->h ----
    k_gram<<<dim3((n + 1023) / 1024, 2), 256, 0, stream>>>(x, perm, typeStart, gram);
    k_ri_coef<<<1, 512, 0, stream>>>(gram, typeStart, ri_w0, ri_b0, ri_g0, ri_be0, w0eff, b0eff);
    k_readin<<<dim3(gmx, 2), 256, 0, stream>>>(x, perm, typeStart, w0eff, b0eff, pw_ri1, ri_b1,
                                               h, h16, SS(1));

    // ---- RES+ layers ----
    for (int l = 0; l < LL; ++l) {
        const int s_cn = l ? 4 : 1, s_mn = l ? 5 : 2, s_mg = l ? 6 : 3, s_nx = l ? 7 : 4;
        k_coef<<<1, 512, 0, stream>>>(SS(s_cn), typeStart, cn_g + (size_t)l * TT * CC,
                                      cn_b + (size_t)l * TT * CC, scale, shift, CC);
        const ushort* wconv = pw_conv + (size_t)l * 640 * 128;
        if (nchunk == 1) {
            k_agg4<<<(n + 3) / 4, 256, 0, stream>>>(h16, rowp2, csr, scale, shift, typeStart, buf, 0, n);
            k_mf<640, 128, false, false, true, false, false, true, 2><<<gmx, 256, 0, stream>>>(
                nullptr, buf, wconv, rg_bias + (size_t)l * CC, nullptr, nullptr, typeStart,
                h, h16, SS(s_mn), 0, 0, n);
        } else {
            for (int q0 = 0; q0 < n; q0 += CHK) {
                const int q1 = min(n, q0 + CHK);
                k_agg4<<<(q1 - q0 + 3) / 4, 256, 0, stream>>>(h16, rowp2, csr, scale, shift,
                                                              typeStart, buf, q0, q1);
                k_mf<640, 128, false, false, true, false, false, false, 0>
                    <<<(q1 - q0 + 127) / 128, 256, 0, stream>>>(
                        nullptr, buf, wconv, rg_bias + (size_t)l * CC, nullptr, nullptr, typeStart,
                        tconv, nullptr, nullptr, q0, q0, q1);
            }
            k_add_stats<<<(n + 255) / 256, 256, 0, stream>>>(h, h16, tconv, typeStart, SS(s_mn), n);
        }

        k_coef<<<1, 512, 0, stream>>>(SS(s_mn), typeStart, mn_g + (size_t)l * TT * CC,
                                      mn_b + (size_t)l * TT * CC, scale, shift, CC);
        k_mf<128, 256, true, true, false, true, true, true, 1><<<dim3(gmx, 2, 2), 256, 0, stream>>>(
            h, nullptr, pw_mw0 + (size_t)l * 2 * 128 * 256, mb0 + (size_t)l * TT * HH,
            scale, shift, typeStart, nullptr, A256b, SS(s_mg), 0, 0, n);
        k_coef<<<1, 512, 0, stream>>>(SS(s_mg), typeStart, mg0 + (size_t)l * TT * HH,
                                      mbe0 + (size_t)l * TT * HH, scale, shift, HH);
        if (l == 0)
            k_mf<256, 128, true, true, true, true, true, true, 2><<<dim3(gmx, 2, 1), 256, 0, stream>>>(
                nullptr, A256b, pw_mw1 + (size_t)l * 2 * 256 * 128, mb1 + (size_t)l * TT * CC,
                scale, shift, typeStart, h, h16, SS(s_nx), 0, 0, n);
        else
            k_mf<256, 128, true, true, true, true, true, false, 2><<<dim3(gmx, 2, 1), 256, 0, stream>>>(
                nullptr, A256b, pw_mw1 + (size_t)l * 2 * 256 * 128, mb1 + (size_t)l * TT * CC,
                scale, shift, typeStart, h, h16, nullptr, 0, 0, n);
    }

    // ---- readout ----
    k_mf<128, 256, true, true, false, false, true, true, 1><<<dim3(gmx, 2, 2), 256, 0, stream>>>(
        h, nullptr, pw_ro0, ro_b0, nullptr, nullptr, typeStart, nullptr, A256b, SS(8), 0, 0, n);
    k_coef<<<1, 512, 0, stream>>>(SS(8), typeStart, ro_g0, ro_be0, scale, shift, HH);
    k_ro1<<<(n + 63) / 64, 256, 0, stream>>>(A256b, perm, typeStart, ro_w1, ro_b1, scale, shift, out, n);
}

// Round 6
// 801.558 us; speedup vs baseline: 10.9565x; 1.0471x over previous
//
#include <hip/hip_runtime.h>

#define TT 2
#define RR 4
#define LL 2
#define DIN 16
#define HH 256
#define CC 128
#define DOUT 4
#define EPS 1e-5f
#define NB 32   // stat buckets
#define NBG 16  // gram buckets

typedef float v4f __attribute__((ext_vector_type(4)));
typedef short bf16x8 __attribute__((ext_vector_type(8)));

__device__ __forceinline__ ushort f2bf(float x) {
    uint u = __float_as_uint(x);
    return (ushort)((u + 0x7fffu + ((u >> 16) & 1u)) >> 16);
}
__device__ __forceinline__ float bf2f(ushort h) { return __uint_as_float(((uint)h) << 16); }
__device__ __forceinline__ int swc(int c) { return c ^ ((c >> 3) & 7); }
__device__ __forceinline__ uint pack2(float x, float y) {
    return (uint)f2bf(x) | ((uint)f2bf(y) << 16);
}

// ---------------------------------------------------------------------------
// hierarchical exclusive scan
__global__ __launch_bounds__(1024) void k_scan1(const int* __restrict__ in, int* __restrict__ out,
                                                int* __restrict__ part, int n) {
    __shared__ int sm[1024];
    const int tid = threadIdx.x;
    const int i = blockIdx.x * 1024 + tid;
    const int v = (i < n) ? in[i] : 0;
    sm[tid] = v;
    __syncthreads();
    for (int off = 1; off < 1024; off <<= 1) {
        const int u = (tid >= off) ? sm[tid - off] : 0;
        __syncthreads();
        sm[tid] += u;
        __syncthreads();
    }
    if (i < n) out[i] = sm[tid] - v;
    if (tid == 1023) part[blockIdx.x] = sm[1023];
}

__global__ __launch_bounds__(1024) void k_scan2(int* __restrict__ part, int nb) {
    __shared__ int sm[1024];
    const int tid = threadIdx.x;
    const int v = (tid < nb) ? part[tid] : 0;
    sm[tid] = v;
    __syncthreads();
    for (int off = 1; off < 1024; off <<= 1) {
        const int u = (tid >= off) ? sm[tid - off] : 0;
        __syncthreads();
        sm[tid] += u;
        __syncthreads();
    }
    if (tid < nb) part[tid] = sm[tid] - v;
    if (tid == nb - 1) part[nb] = sm[tid];
}

// scan3 + optional typeStart write (pscan path) + optional dual write (cursor copy)
__global__ __launch_bounds__(1024) void k_scan3(int* __restrict__ arr, const int* __restrict__ part,
                                                int n, int nb, int* __restrict__ typeStart,
                                                int* __restrict__ out2) {
    const int i = blockIdx.x * 1024 + threadIdx.x;
    if (i < n) {
        const int v = arr[i] + part[i >> 10];
        arr[i] = v;
        if (out2) out2[i] = v;
    } else if (i == n) {
        const int total = part[nb];
        arr[n] = total;
        if (typeStart) { typeStart[0] = 0; typeStart[1] = n - total; typeStart[2] = n; }
    }
}

__global__ __launch_bounds__(256) void k_build_perm(const int* __restrict__ nt, const int* __restrict__ pscan,
                                                    const int* __restrict__ typeStart, int* __restrict__ perm,
                                                    int* __restrict__ inv, int n) {
    const int i = blockIdx.x * 256 + threadIdx.x;
    if (i >= n) return;
    const int s1 = pscan[i];
    const int pos = nt[i] ? (typeStart[1] + s1) : (i - s1);
    perm[pos] = i;
    inv[i] = pos;
}

__global__ __launch_bounds__(256) void k_deg2(const int* __restrict__ dstv, const int* __restrict__ et,
                                              const int* __restrict__ inv, int* __restrict__ rowp2, int nE) {
    const int e = blockIdx.x * 256 + threadIdx.x;
    if (e < nE) atomicAdd(&rowp2[inv[dstv[e]] * 4 + et[e]], 1);
}

__global__ __launch_bounds__(256) void k_fill2(const int* __restrict__ srcv, const int* __restrict__ dstv,
                                               const int* __restrict__ et, const int* __restrict__ inv,
                                               int* __restrict__ cur, int* __restrict__ csr, int nE) {
    const int e = blockIdx.x * 256 + threadIdx.x;
    if (e < nE) {
        const int pos = atomicAdd(&cur[inv[dstv[e]] * 4 + et[e]], 1);
        csr[pos] = inv[srcv[e]];
    }
}

// ---------------------------------------------------------------------------
// all regular weight packs in one kernel: [nmat][K][N] f32 -> [mat][K/8][N][8] bf16
__global__ __launch_bounds__(256) void k_packall(const float* __restrict__ ri_w1, const float* __restrict__ mw0,
                                                 const float* __restrict__ mw1, const float* __restrict__ ro_w0,
                                                 ushort* __restrict__ p_ri1, ushort* __restrict__ p_mw0,
                                                 ushort* __restrict__ p_mw1, ushort* __restrict__ p_ro0) {
    for (long long idx = (long long)blockIdx.x * 256 + threadIdx.x; idx < 393216;
         idx += (long long)gridDim.x * 256) {
        const float* src; ushort* dst; int K, N; long long lo;
        if (idx < 65536)       { src = ri_w1; dst = p_ri1; K = 256; N = 128; lo = idx; }
        else if (idx < 196608) { src = mw0;   dst = p_mw0; K = 128; N = 256; lo = idx - 65536; }
        else if (idx < 327680) { src = mw1;   dst = p_mw1; K = 256; N = 128; lo = idx - 196608; }
        else                   { src = ro_w0; dst = p_ro0; K = 128; N = 256; lo = idx - 327680; }
        const int kn = K * N;
        const int mat = (int)(lo / kn);
        const int rem = (int)(lo - (long long)mat * kn);
        const int k = rem / N, col = rem % N;
        dst[((size_t)mat * (K / 8) + (k >> 3)) * N * 8 + (size_t)col * 8 + (k & 7)] = f2bf(src[lo]);
    }
}

// conv stacked W: rows 0..511 = rg_w[r][kin][col], rows 512..639 = root[k][col]; blockIdx.y = layer
__global__ __launch_bounds__(256) void k_pack_conv(const float* __restrict__ rgw_all,
                                                   const float* __restrict__ root_all,
                                                   ushort* __restrict__ dst_all) {
    const int idx = blockIdx.x * 256 + threadIdx.x;
    if (idx >= 640 * 128) return;
    const int l = blockIdx.y;
    const float* rgw = rgw_all + (size_t)l * RR * CC * CC;
    const float* root = root_all + (size_t)l * CC * CC;
    ushort* dst = dst_all + (size_t)l * 640 * 128;
    const int k = idx >> 7, col = idx & 127;
    const float v = (k < 512) ? rgw[(((k >> 7) * CC) + (k & 127)) * CC + col]
                              : root[(size_t)(k - 512) * CC + col];
    dst[((size_t)(k >> 3) * CC + col) * 8 + (k & 7)] = f2bf(v);
}

// ---------------------------------------------------------------------------
// bucketed stats -> scale/shift
__global__ __launch_bounds__(512) void k_coef(const float* __restrict__ stat, const int* __restrict__ typeStart,
                                              const float* __restrict__ g, const float* __restrict__ be,
                                              float* __restrict__ scale, float* __restrict__ shift, int F) {
    const int tid = threadIdx.x;
    if (tid >= TT * F) return;
    const int t = tid / F;
    float s = 0.f, q = 0.f;
    for (int b = 0; b < NB; ++b) {
        s += stat[(size_t)b * 1024 + tid];
        q += stat[(size_t)b * 1024 + 512 + tid];
    }
    const float cnt = fmaxf((float)(typeStart[t + 1] - typeStart[t]), 1.f);
    const float mean = s / cnt;
    const float var = q / cnt - mean * mean;
    const float sc = g[tid] * rsqrtf(var + EPS);
    scale[tid] = sc;
    shift[tid] = be[tid] - mean * sc;
}

// ---------------------------------------------------------------------------
// y16 = act(bn(h))  (f32 h master -> bf16), per-type coef
__global__ __launch_bounds__(256) void k_bnact(const float* __restrict__ h, const float* __restrict__ scale,
                                               const float* __restrict__ shift, const int* __restrict__ typeStart,
                                               ushort* __restrict__ y16, int n) {
    const int c0 = typeStart[1];
    const long long total = (long long)n * 32;
    for (long long idx = (long long)blockIdx.x * 256 + threadIdx.x; idx < total;
         idx += (long long)gridDim.x * 256) {
        const int i = (int)(idx >> 5), cq = (int)(idx & 31);
        const int t = (i >= c0) ? 1 : 0;
        const v4f v = *(const v4f*)(h + (size_t)i * CC + cq * 4);
        const v4f sc = *(const v4f*)(scale + t * CC + cq * 4);
        const v4f sf = *(const v4f*)(shift + t * CC + cq * 4);
        float o[4];
#pragma unroll
        for (int j = 0; j < 4; ++j) {
            const float vv = fmaf(v[j], sc[j], sf[j]);
            o[j] = fmaxf(vv, 0.01f * vv);
        }
        uint2 p = make_uint2(pack2(o[0], o[1]), pack2(o[2], o[3]));
        *(uint2*)((uint*)y16 + (size_t)i * 64 + cq * 2) = p;
    }
}

// ---------------------------------------------------------------------------
// 4-relation aggregation of precomputed y16 -> bf16 buf [rows][512], nontemporal
__global__ __launch_bounds__(256) void k_agg4(const ushort* __restrict__ y16, const int* __restrict__ rowp2,
                                              const int* __restrict__ csr, ushort* __restrict__ buf,
                                              int q0, int q1) {
    const int wid = threadIdx.x >> 6, lane = threadIdx.x & 63;
    const int i = q0 + blockIdx.x * 4 + wid;
    if (i >= q1) return;
    const uint* y32 = (const uint*)y16;
    float2 a0 = {0.f, 0.f}, a1 = {0.f, 0.f}, a2 = {0.f, 0.f}, a3 = {0.f, 0.f};
    const int e0 = rowp2[4 * i], b1 = rowp2[4 * i + 1], b2 = rowp2[4 * i + 2],
              b3 = rowp2[4 * i + 3], e1 = rowp2[4 * i + 4];
    for (int e = e0; e < e1; e += 64) {
        const int cnt = min(64, e1 - e);
        int pk = (lane < cnt) ? csr[e + lane] : 0;
        for (int j = 0; j < cnt; ++j) {
            const int s = __shfl(pk, j);
            const uint u = y32[(size_t)s * 64 + lane];
            const float vx = bf2f((ushort)(u & 0xffff));
            const float vy = bf2f((ushort)(u >> 16));
            const int idx = e + j;
            if (idx < b1)      { a0.x += vx; a0.y += vy; }
            else if (idx < b2) { a1.x += vx; a1.y += vy; }
            else if (idx < b3) { a2.x += vx; a2.y += vy; }
            else               { a3.x += vx; a3.y += vy; }
        }
    }
    uint* brow = (uint*)buf + (size_t)(i - q0) * 256;
    __builtin_nontemporal_store(pack2(a0.x, a0.y), brow + 0 * 64 + lane);
    __builtin_nontemporal_store(pack2(a1.x, a1.y), brow + 1 * 64 + lane);
    __builtin_nontemporal_store(pack2(a2.x, a2.y), brow + 2 * 64 + lane);
    __builtin_nontemporal_store(pack2(a3.x, a3.y), brow + 3 * 64 + lane);
}

// ---------------------------------------------------------------------------
// Gram matrix of x per type: gram[t][bucket][272] = {G[256], s[16]}
__global__ __launch_bounds__(256) void k_gram(const float* __restrict__ x, const int* __restrict__ perm,
                                              const int* __restrict__ typeStart, float* __restrict__ gram) {
    __shared__ float Xs[256][17];
    const int tid = threadIdx.x;
    const int t = blockIdx.y;
    const int rbeg = typeStart[t], rend = typeStart[t + 1];
    const int r0 = rbeg + blockIdx.x * 1024;
    if (r0 >= rend) return;
    const int i = tid >> 4, j = tid & 15;
    float acc = 0.f, sacc = 0.f;
    for (int rr = 0; rr < 4; ++rr) {
        const int gr = r0 + rr * 256 + tid;
        v4f x0 = 0.f, x1 = 0.f, x2 = 0.f, x3 = 0.f;
        if (gr < rend) {
            const float* xr = x + (size_t)perm[gr] * DIN;
            x0 = *(const v4f*)xr; x1 = *(const v4f*)(xr + 4);
            x2 = *(const v4f*)(xr + 8); x3 = *(const v4f*)(xr + 12);
        }
        __syncthreads();
#pragma unroll
        for (int e = 0; e < 4; ++e) { Xs[tid][e] = x0[e]; Xs[tid][4 + e] = x1[e];
                                      Xs[tid][8 + e] = x2[e]; Xs[tid][12 + e] = x3[e]; }
        __syncthreads();
        for (int r = 0; r < 256; ++r) acc += Xs[r][i] * Xs[r][j];
        if (tid < 16)
            for (int r = 0; r < 256; ++r) sacc += Xs[r][tid];
        __syncthreads();
    }
    float* gb = gram + ((size_t)t * NBG + (blockIdx.x & (NBG - 1))) * 272;
    atomicAdd(&gb[tid], acc);
    if (tid < 16) atomicAdd(&gb[256 + tid], sacc);
}

// analytic readin BN coef, folded into effective W0', b0'
__global__ __launch_bounds__(512) void k_ri_coef(const float* __restrict__ gram, const int* __restrict__ typeStart,
                                                 const float* __restrict__ ri_w0, const float* __restrict__ ri_b0,
                                                 const float* __restrict__ g, const float* __restrict__ be,
                                                 float* __restrict__ w0eff, float* __restrict__ b0eff) {
    __shared__ float G[2][272];
    const int tid = threadIdx.x;
    for (int idx = tid; idx < 2 * 272; idx += 512) {
        const int tt = idx / 272, k = idx % 272;
        float s = 0.f;
        for (int b = 0; b < NBG; ++b) s += gram[((size_t)tt * NBG + b) * 272 + k];
        G[tt][k] = s;
    }
    __syncthreads();
    const int t = tid >> 8, c = tid & 255;
    float wv[16];
#pragma unroll
    for (int k = 0; k < 16; ++k) wv[k] = ri_w0[((size_t)t * 16 + k) * HH + c];
    const float b = ri_b0[t * HH + c];
    const float cnt = fmaxf((float)(typeStart[t + 1] - typeStart[t]), 1.f);
    float sw = 0.f;
#pragma unroll
    for (int k = 0; k < 16; ++k) sw += G[t][256 + k] * wv[k];
    const float mean = (sw + cnt * b) / cnt;
    float e2 = 0.f;
#pragma unroll
    for (int i = 0; i < 16; ++i) {
        const float wi = wv[i];
#pragma unroll
        for (int j = 0; j < 16; ++j) e2 += wi * wv[j] * G[t][i * 16 + j];
    }
    e2 = (e2 + 2.f * b * sw + cnt * b * b) / cnt;
    const float var = e2 - mean * mean;
    const float sc = g[t * HH + c] * rsqrtf(var + EPS);
    const float sf = be[t * HH + c] - mean * sc;
    b0eff[t * HH + c] = b * sc + sf;
#pragma unroll
    for (int k = 0; k < 16; ++k) w0eff[((size_t)t * 16 + k) * HH + c] = wv[k] * sc;
}

// ---------------------------------------------------------------------------
// fused readin: h = act(x@W0'+b0') @ ri_w1 + ri_b1 ; writes h, h16, stats slot
__global__ __launch_bounds__(256) void k_readin(const float* __restrict__ x, const int* __restrict__ perm,
                                                const int* __restrict__ typeStart,
                                                const float* __restrict__ w0eff, const float* __restrict__ b0eff,
                                                const ushort* __restrict__ Wp, const float* __restrict__ b1,
                                                float* __restrict__ h, ushort* __restrict__ h16,
                                                float* __restrict__ stat) {
    __shared__ float Xs[128][17];
    __shared__ float W0s[16][256];
    __shared__ float b0s[256];
    __shared__ ushort As[128][40];
    __shared__ ushort Ws[4][128][8];

    const int tid = threadIdx.x;
    const int lane = tid & 63;
    const int wid = tid >> 6;
    const int woffm = (wid >> 1) * 64, woffn = (wid & 1) * 64;
    const int t = blockIdx.y;
    const int rbeg = typeStart[t], rend = typeStart[t + 1];
    const int r0 = rbeg + blockIdx.x * 128;
    if (r0 >= rend) return;

    for (int idx = tid; idx < 16 * 256; idx += 256) W0s[idx >> 8][idx & 255] = w0eff[(size_t)t * 4096 + idx];
    if (tid < 256) b0s[tid] = b0eff[t * 256 + tid];

    const int srow = tid >> 1, half = tid & 1;
    const int sgr = r0 + srow;
    const bool svalid = sgr < rend;
    {
        v4f x0 = 0.f, x1 = 0.f;
        if (svalid) {
            const float* xr = x + (size_t)perm[sgr] * DIN + half * 8;
            x0 = *(const v4f*)xr; x1 = *(const v4f*)(xr + 4);
        }
#pragma unroll
        for (int e = 0; e < 4; ++e) { Xs[srow][half * 8 + e] = x0[e]; Xs[srow][half * 8 + 4 + e] = x1[e]; }
    }
    __syncthreads();
    float xr[16];
#pragma unroll
    for (int k = 0; k < 16; ++k) xr[k] = Xs[srow][k];

    v4f acc[4][4];
#pragma unroll
    for (int mt = 0; mt < 4; ++mt)
#pragma unroll
        for (int nt = 0; nt < 4; ++nt) acc[mt][nt] = (v4f){0.f, 0.f, 0.f, 0.f};

    const size_t wmat = (size_t)t * 256 * 128;
    const int wcp = tid & 63;

    for (int kt = 0; kt < 8; ++kt) {
        const int k0 = kt * 32;
        ushort hA[16];
#pragma unroll
        for (int c2 = 0; c2 < 16; ++c2) {
            const int col = k0 + half * 16 + c2;
            float d = b0s[col];
#pragma unroll
            for (int k = 0; k < 16; ++k) d = fmaf(xr[k], W0s[k][col], d);
            d = fmaxf(d, 0.01f * d);
            hA[c2] = f2bf(d);
        }
        const ushort* wsrc = Wp + wmat + ((size_t)(k0 / 8 + wid) * 128) * 8 + (size_t)wcp * 16;
        const uint4 w0 = *(const uint4*)wsrc;
        const uint4 w1 = *(const uint4*)(wsrc + 8);
        __syncthreads();
        *(uint4*)&As[srow][half * 16] = *(uint4*)&hA[0];
        *(uint4*)&As[srow][half * 16 + 8] = *(uint4*)&hA[8];
        *(uint4*)&Ws[wid][swc(wcp * 2)][0] = w0;
        *(uint4*)&Ws[wid][swc(wcp * 2 + 1)][0] = w1;
        __syncthreads();
        const int afr = lane & 15;
        const int akg = (lane >> 4) * 8;
        bf16x8 aF[4], wf[4];
#pragma unroll
        for (int mt = 0; mt < 4; ++mt) aF[mt] = *(const bf16x8*)&As[woffm + mt * 16 + afr][akg];
#pragma unroll
        for (int nt = 0; nt < 4; ++nt) wf[nt] = *(const bf16x8*)&Ws[lane >> 4][swc(woffn + nt * 16 + afr)][0];
#pragma unroll
        for (int mt = 0; mt < 4; ++mt)
#pragma unroll
            for (int nt = 0; nt < 4; ++nt)
                acc[mt][nt] = __builtin_amdgcn_mfma_f32_16x16x32_bf16(aF[mt], wf[nt], acc[mt][nt], 0, 0, 0);
    }

    float bv[4];
#pragma unroll
    for (int nt = 0; nt < 4; ++nt) bv[nt] = b1[t * 128 + woffn + nt * 16 + (lane & 15)];
    float cs[4] = {0.f, 0.f, 0.f, 0.f}, cq[4] = {0.f, 0.f, 0.f, 0.f};
#pragma unroll
    for (int mt = 0; mt < 4; ++mt) {
        const int grow = r0 + woffm + mt * 16 + (lane >> 4) * 4;
#pragma unroll
        for (int nt = 0; nt < 4; ++nt) {
            const int gcol = woffn + nt * 16 + (lane & 15);
#pragma unroll
            for (int rg = 0; rg < 4; ++rg) {
                const int gr = grow + rg;
                if (gr < rend) {
                    const float v = acc[mt][nt][rg] + bv[nt];
                    const size_t o = (size_t)gr * 128 + gcol;
                    h[o] = v;
                    h16[o] = f2bf(v);
                    cs[nt] += v; cq[nt] += v * v;
                }
            }
        }
    }
    float* sb = stat + (size_t)(blockIdx.x & (NB - 1)) * 1024;
#pragma unroll
    for (int nt = 0; nt < 4; ++nt) {
        float s = cs[nt], q = cq[nt];
        s += __shfl_xor(s, 16); q += __shfl_xor(q, 16);
        s += __shfl_xor(s, 32); q += __shfl_xor(q, 32);
        if (lane < 16) {
            const int col = t * 128 + woffn + nt * 16 + lane;
            atomicAdd(&sb[col], s);
            atomicAdd(&sb[512 + col], q);
        }
    }
}

// ---------------------------------------------------------------------------
// MFMA GEMM (bf16). XBF: X bf16 rows (offset rbase, stride K). CROOT: K=640 conv
// split operand (buf[512-wide] + y16[128-wide] tail). BNIN: scale/shift+leaky.
// OUTMODE 0: Y=f32; 1: Y16=bf16; 2: h-accumulate (Y+=, Y16=bf16(h)).
template <int K, int OUTW, bool TYPED, bool WHET, bool XBF, bool CROOT, bool BNIN,
          bool BHET, bool STATS, int OUTMODE>
__global__ __launch_bounds__(256) void k_mf(
    const float* __restrict__ Xf, const ushort* __restrict__ Xb, const ushort* __restrict__ Xb2,
    const ushort* __restrict__ Wp, const float* __restrict__ Bb,
    const float* __restrict__ scale, const float* __restrict__ shift,
    const int* __restrict__ typeStart, float* __restrict__ Y,
    ushort* __restrict__ Y16, float* __restrict__ stat,
    int rbase, int rbeg_u, int rend_u) {
    __shared__ ushort As[128][40];
    __shared__ ushort Ws[4][128][8];
    __shared__ float csh[BNIN ? K : 1];
    __shared__ float cfh[BNIN ? K : 1];

    constexpr int XSTR = CROOT ? 512 : K;

    const int tid = threadIdx.x;
    const int lane = tid & 63;
    const int wid = tid >> 6;
    const int woffm = (wid >> 1) * 64, woffn = (wid & 1) * 64;

    int t = 0, rbeg = rbeg_u, rend = rend_u;
    if constexpr (TYPED) { t = blockIdx.y; rbeg = typeStart[t]; rend = typeStart[t + 1]; }
    const int r0 = rbeg + blockIdx.x * 128;
    if (r0 >= rend) return;
    const int zoff = (OUTW == 256) ? blockIdx.z * 128 : 0;

    if constexpr (BNIN) {
        for (int k = tid; k < K; k += 256) { csh[k] = scale[t * K + k]; cfh[k] = shift[t * K + k]; }
        __syncthreads();
    }

    const int srow = tid >> 1, scg = (tid & 1) * 16;
    const int sgr = r0 + srow;
    const bool svalid = sgr < rend;
    const int wcp = tid & 63;

    v4f acc[4][4];
#pragma unroll
    for (int mt = 0; mt < 4; ++mt)
#pragma unroll
        for (int nt = 0; nt < 4; ++nt) acc[mt][nt] = (v4f){0.f, 0.f, 0.f, 0.f};

    const size_t wmat = (size_t)(WHET ? t : 0) * K * OUTW;

    for (int kt = 0; kt < K / 32; ++kt) {
        const int k0 = kt * 32;
        uint uu[8];
        if constexpr (XBF) {
            const ushort* xs;
            if constexpr (CROOT) {
                xs = (k0 >= 512) ? (Xb2 + (size_t)sgr * 128 + (k0 - 512) + scg)
                                 : (Xb + (size_t)(sgr - rbase) * XSTR + k0 + scg);
            } else {
                xs = Xb + (size_t)(sgr - rbase) * XSTR + k0 + scg;
            }
            uint4 a0 = make_uint4(0, 0, 0, 0), a1 = make_uint4(0, 0, 0, 0);
            if (svalid) {
                a0 = *(const uint4*)xs;
                a1 = *(const uint4*)(xs + 8);
            }
            uu[0] = a0.x; uu[1] = a0.y; uu[2] = a0.z; uu[3] = a0.w;
            uu[4] = a1.x; uu[5] = a1.y; uu[6] = a1.z; uu[7] = a1.w;
            if constexpr (BNIN) {
#pragma unroll
                for (int e = 0; e < 8; ++e) {
                    const int k = k0 + scg + 2 * e;
                    float f0 = fmaf(bf2f((ushort)(uu[e] & 0xffff)), csh[k], cfh[k]);
                    float f1 = fmaf(bf2f((ushort)(uu[e] >> 16)), csh[k + 1], cfh[k + 1]);
                    f0 = fmaxf(f0, 0.01f * f0);
                    f1 = fmaxf(f1, 0.01f * f1);
                    uu[e] = pack2(f0, f1);
                }
            }
        } else {
            float fv[16];
            {
                v4f av0 = 0.f, av1 = 0.f, av2 = 0.f, av3 = 0.f;
                if (svalid) {
                    const float* xs = Xf + (size_t)sgr * K + k0 + scg;
                    av0 = *(const v4f*)xs; av1 = *(const v4f*)(xs + 4);
                    av2 = *(const v4f*)(xs + 8); av3 = *(const v4f*)(xs + 12);
                }
#pragma unroll
                for (int e = 0; e < 4; ++e) { fv[e] = av0[e]; fv[4 + e] = av1[e];
                                              fv[8 + e] = av2[e]; fv[12 + e] = av3[e]; }
            }
            if constexpr (BNIN) {
#pragma unroll
                for (int e = 0; e < 16; ++e) {
                    const int k = k0 + scg + e;
                    float vv = fmaf(fv[e], csh[k], cfh[k]);
                    fv[e] = fmaxf(vv, 0.01f * vv);
                }
            }
#pragma unroll
            for (int e = 0; e < 8; ++e) uu[e] = pack2(fv[2 * e], fv[2 * e + 1]);
        }
        const ushort* wsrc = Wp + wmat + ((size_t)(k0 / 8 + wid) * OUTW + zoff) * 8 + (size_t)wcp * 16;
        const uint4 w0 = *(const uint4*)wsrc;
        const uint4 w1 = *(const uint4*)(wsrc + 8);

        __syncthreads();
        *(uint4*)&As[srow][scg] = make_uint4(uu[0], uu[1], uu[2], uu[3]);
        *(uint4*)&As[srow][scg + 8] = make_uint4(uu[4], uu[5], uu[6], uu[7]);
        *(uint4*)&Ws[wid][swc(wcp * 2)][0] = w0;
        *(uint4*)&Ws[wid][swc(wcp * 2 + 1)][0] = w1;
        __syncthreads();

        const int afr = lane & 15;
        const int akg = (lane >> 4) * 8;
        bf16x8 aF[4], wf[4];
#pragma unroll
        for (int mt = 0; mt < 4; ++mt) aF[mt] = *(const bf16x8*)&As[woffm + mt * 16 + afr][akg];
#pragma unroll
        for (int nt = 0; nt < 4; ++nt) wf[nt] = *(const bf16x8*)&Ws[lane >> 4][swc(woffn + nt * 16 + afr)][0];
#pragma unroll
        for (int mt = 0; mt < 4; ++mt)
#pragma unroll
            for (int nt = 0; nt < 4; ++nt)
                acc[mt][nt] = __builtin_amdgcn_mfma_f32_16x16x32_bf16(aF[mt], wf[nt], acc[mt][nt], 0, 0, 0);
    }

    // ---- epilogue ----
    const float* BbT = Bb + (BHET ? (size_t)t * OUTW : 0);
    float bv[4];
#pragma unroll
    for (int nt = 0; nt < 4; ++nt) bv[nt] = BbT[zoff + woffn + nt * 16 + (lane & 15)];
    const int c0 = (STATS && !TYPED) ? typeStart[1] : 0;
    float cs0[4] = {0.f, 0.f, 0.f, 0.f}, cq0[4] = {0.f, 0.f, 0.f, 0.f};
    float cs1[4] = {0.f, 0.f, 0.f, 0.f}, cq1[4] = {0.f, 0.f, 0.f, 0.f};
#pragma unroll
    for (int mt = 0; mt < 4; ++mt) {
        const int grow = r0 + woffm + mt * 16 + (lane >> 4) * 4;
#pragma unroll
        for (int nt = 0; nt < 4; ++nt) {
            const int gcol = zoff + woffn + nt * 16 + (lane & 15);
#pragma unroll
            for (int rg = 0; rg < 4; ++rg) {
                const int gr = grow + rg;
                if (gr < rend) {
                    float v = acc[mt][nt][rg] + bv[nt];
                    const size_t o = (size_t)gr * OUTW + gcol;
                    if constexpr (OUTMODE == 0) Y[o] = v;
                    if constexpr (OUTMODE == 1) Y16[o] = f2bf(v);
                    if constexpr (OUTMODE == 2) {
                        const float hv = Y[o] + v;
                        Y[o] = hv;
                        Y16[o] = f2bf(hv);
                        v = hv;
                    }
                    if constexpr (STATS) {
                        if (TYPED || gr < c0) { cs0[nt] += v; cq0[nt] += v * v; }
                        else                  { cs1[nt] += v; cq1[nt] += v * v; }
                    }
                }
            }
        }
    }
    if constexpr (STATS) {
        float* sb = stat + (size_t)(blockIdx.x & (NB - 1)) * 1024;
#pragma unroll
        for (int nt = 0; nt < 4; ++nt) {
            float s = cs0[nt], q = cq0[nt];
            s += __shfl_xor(s, 16); q += __shfl_xor(q, 16);
            s += __shfl_xor(s, 32); q += __shfl_xor(q, 32);
            if (lane < 16) {
                const int col = t * OUTW + zoff + woffn + nt * 16 + lane;
                atomicAdd(&sb[col], s);
                atomicAdd(&sb[512 + col], q);
            }
            if constexpr (!TYPED) {
                float s1 = cs1[nt], q1 = cq1[nt];
                s1 += __shfl_xor(s1, 16); q1 += __shfl_xor(q1, 16);
                s1 += __shfl_xor(s1, 32); q1 += __shfl_xor(q1, 32);
                if (lane < 16) {
                    const int col = OUTW + zoff + woffn + nt * 16 + lane;
                    atomicAdd(&sb[col], s1);
                    atomicAdd(&sb[512 + col], q1);
                }
            }
        }
    }
}

// ---------------------------------------------------------------------------
// readout stage 2: out[perm[i]] = act(bn(A256b[i])) @ ro_w1[t] + ro_b1[t]
__global__ __launch_bounds__(256) void k_ro1(const ushort* __restrict__ A256b, const int* __restrict__ perm,
                                             const int* __restrict__ typeStart, const float* __restrict__ ro_w1,
                                             const float* __restrict__ ro_b1, const float* __restrict__ scale,
                                             const float* __restrict__ shift, float* __restrict__ out, int n) {
    __shared__ float W1s[2][256][4];
    __shared__ float scs[512];
    __shared__ float sfs[512];
    const int tid = threadIdx.x;
    for (int idx = tid; idx < 2048; idx += 256) {
        const int t = idx >> 10, rem = idx & 1023;
        W1s[t][rem >> 2][rem & 3] = ro_w1[idx];
    }
    for (int idx = tid; idx < 512; idx += 256) { scs[idx] = scale[idx]; sfs[idx] = shift[idx]; }
    __syncthreads();
    const int trow = tid >> 2, sub = tid & 3;
    const int gr = blockIdx.x * 64 + trow;
    if (gr >= n) return;
    const int c0 = typeStart[1];
    const int t = (gr >= c0) ? 1 : 0;
    v4f acc = 0.f;
    const ushort* ar = A256b + (size_t)gr * 256 + sub * 64;
#pragma unroll
    for (int q = 0; q < 8; ++q) {
        const uint4 u = *(const uint4*)(ar + q * 8);
        const uint uw[4] = {u.x, u.y, u.z, u.w};
#pragma unroll
        for (int e = 0; e < 4; ++e) {
#pragma unroll
            for (int hl = 0; hl < 2; ++hl) {
                const int col = sub * 64 + q * 8 + 2 * e + hl;
                const float v = bf2f((ushort)(hl ? (uw[e] >> 16) : (uw[e] & 0xffff)));
                float vv = fmaf(v, scs[t * 256 + col], sfs[t * 256 + col]);
                vv = fmaxf(vv, 0.01f * vv);
                acc += vv * *(const v4f*)&W1s[t][col][0];
            }
        }
    }
#pragma unroll
    for (int e = 0; e < 4; ++e) { acc[e] += __shfl_xor(acc[e], 1); acc[e] += __shfl_xor(acc[e], 2); }
    if (sub == 0) {
        acc += *(const v4f*)(ro_b1 + t * 4);
        *(v4f*)(out + (size_t)perm[gr] * 4) = acc;
    }
}

// ---------------------------------------------------------------------------
extern "C" void kernel_launch(void* const* d_in, const int* in_sizes, int n_in,
                              void* d_out, int out_size, void* d_ws, size_t ws_size,
                              hipStream_t stream) {
    const float* x = (const float*)d_in[0];
    const int* ei = (const int*)d_in[1];
    const int* nt = (const int*)d_in[2];
    const int* et = (const int*)d_in[3];
    const float* ri_w0 = (const float*)d_in[4];
    const float* ri_b0 = (const float*)d_in[5];
    const float* ri_g0 = (const float*)d_in[6];
    const float* ri_be0 = (const float*)d_in[7];
    const float* ri_w1 = (const float*)d_in[8];
    const float* ri_b1 = (const float*)d_in[9];
    const float* cn_g = (const float*)d_in[10];
    const float* cn_b = (const float*)d_in[11];
    const float* rg_w = (const float*)d_in[12];
    const float* rg_root = (const float*)d_in[13];
    const float* rg_bias = (const float*)d_in[14];
    const float* mn_g = (const float*)d_in[15];
    const float* mn_b = (const float*)d_in[16];
    const float* mw0 = (const float*)d_in[17];
    const float* mb0 = (const float*)d_in[18];
    const float* mg0 = (const float*)d_in[19];
    const float* mbe0 = (const float*)d_in[20];
    const float* mw1 = (const float*)d_in[21];
    const float* mb1 = (const float*)d_in[22];
    const float* ro_w0 = (const float*)d_in[23];
    const float* ro_b0 = (const float*)d_in[24];
    const float* ro_g0 = (const float*)d_in[25];
    const float* ro_be0 = (const float*)d_in[26];
    const float* ro_w1 = (const float*)d_in[27];
    const float* ro_b1 = (const float*)d_in[28];

    const int n = in_sizes[2];
    const int nE = in_sizes[3];
    const int* srcv = ei;
    const int* dstv = ei + nE;

    // ---- workspace ----
    char* w = (char*)d_ws;
    size_t off = 0;
    auto alloc = [&](size_t bytes) -> char* {
        char* p = w + off;
        off = (off + bytes + 255) & ~(size_t)255;
        return p;
    };
    float* h = (float*)alloc((size_t)n * CC * sizeof(float));
    ushort* h16 = (ushort*)alloc((size_t)n * CC * sizeof(ushort));
    int* csr = (int*)alloc((size_t)nE * sizeof(int));
    int* rowp2 = (int*)alloc(((size_t)4 * n + 1) * sizeof(int));
    int* cur2 = (int*)alloc((size_t)4 * n * sizeof(int));
    int* perm = (int*)alloc((size_t)n * sizeof(int));
    int* inv = (int*)alloc((size_t)n * sizeof(int));
    int* pscan = (int*)alloc((size_t)(n + 1) * sizeof(int));
    int* part = (int*)alloc(2052 * sizeof(int));
    int* typeStart = (int*)alloc(64);
    float* statgram = (float*)alloc(((size_t)9 * NB * 1024 + 2 * NBG * 272) * sizeof(float));
    float* scale = (float*)alloc(512 * sizeof(float));
    float* shift = (float*)alloc(512 * sizeof(float));
    float* w0eff = (float*)alloc((size_t)2 * 16 * 256 * sizeof(float));
    float* b0eff = (float*)alloc(512 * sizeof(float));
    ushort* pw_ri1 = (ushort*)alloc(65536 * 2);
    ushort* pw_mw0 = (ushort*)alloc(131072 * 2);
    ushort* pw_mw1 = (ushort*)alloc(131072 * 2);
    ushort* pw_ro0 = (ushort*)alloc(65536 * 2);
    ushort* pw_conv = (ushort*)alloc(163840 * 2);
    char* region2 = alloc((size_t)n * 512);  // A256b bf16 | y16 (disjoint lifetimes)
    if (ws_size < off) return;

    float* statbuf = statgram;
    float* gram = statgram + (size_t)9 * NB * 1024;
    ushort* A256b = (ushort*)region2;
    ushort* y16 = (ushort*)region2;  // first n*256 bytes of region2
    float* out = (float*)d_out;

    // remaining workspace -> conv aggregation buffer (bf16 [rows][512])
    ushort* buf = (ushort*)(w + off);
    const size_t bufBytes = (ws_size > off) ? (ws_size - off) : 0;
    const long long chkcap = (long long)(bufBytes / 1024);
    if (chkcap < 1024) return;
    int nchunk, CHK;
    if (chkcap >= n) { nchunk = 1; CHK = n; }
    else { nchunk = (int)((n + chkcap - 1) / chkcap); CHK = (n + nchunk - 1) / nchunk; }

    auto SS = [&](int slot) { return statbuf + (size_t)slot * NB * 1024; };

    const int gE = (nE + 255) / 256;
    const int gN = (n + 255) / 256;
    const int nb = (n + 1023) / 1024;
    const int m4 = 4 * n;
    const int nb2 = (m4 + 1023) / 1024;
    const int gmx = (n + 127) / 128;

    // ---- weight packing ----
    k_packall<<<1536, 256, 0, stream>>>(ri_w1, mw0, mw1, ro_w0, pw_ri1, pw_mw0, pw_mw1, pw_ro0);
    k_pack_conv<<<dim3(320, 2), 256, 0, stream>>>(rg_w, rg_root, pw_conv);

    // ---- setup ----
    hipMemsetAsync(statgram, 0, ((size_t)9 * NB * 1024 + 2 * NBG * 272) * sizeof(float), stream);
    k_scan1<<<nb, 1024, 0, stream>>>(nt, pscan, part, n);
    k_scan2<<<1, 1024, 0, stream>>>(part, nb);
    k_scan3<<<(n + 1024) / 1024, 1024, 0, stream>>>(pscan, part, n, nb, typeStart, nullptr);
    k_build_perm<<<gN, 256, 0, stream>>>(nt, pscan, typeStart, perm, inv, n);
    hipMemsetAsync(rowp2, 0, ((size_t)m4 + 1) * sizeof(int), stream);
    k_deg2<<<gE, 256, 0, stream>>>(dstv, et, inv, rowp2, nE);
    k_scan1<<<nb2, 1024, 0, stream>>>(rowp2, rowp2, part, m4);
    k_scan2<<<1, 1024, 0, stream>>>(part, nb2);
    k_scan3<<<(m4 + 1024) / 1024, 1024, 0, stream>>>(rowp2, part, m4, nb2, nullptr, cur2);
    k_fill2<<<gE, 256, 0, stream>>>(srcv, dstv, et, inv, cur2, csr, nE);

    // ---- readin (fused): gram -> analytic coef -> x->h ----
    k_gram<<<dim3((n + 1023) / 1024, 2), 256, 0, stream>>>(x, perm, typeStart, gram);
    k_ri_coef<<<1, 512, 0, stream>>>(gram, typeStart, ri_w0, ri_b0, ri_g0, ri_be0, w0eff, b0eff);
    k_readin<<<dim3(gmx, 2), 256, 0, stream>>>(x, perm, typeStart, w0eff, b0eff, pw_ri1, ri_b1,
                                               h, h16, SS(1));

    // ---- RES+ layers ----
    for (int l = 0; l < LL; ++l) {
        const int s_cn = l ? 4 : 1, s_mn = l ? 5 : 2, s_mg = l ? 6 : 3, s_nx = l ? 7 : 4;
        k_coef<<<1, 512, 0, stream>>>(SS(s_cn), typeStart, cn_g + (size_t)l * TT * CC,
                                      cn_b + (size_t)l * TT * CC, scale, shift, CC);
        k_bnact<<<4096, 256, 0, stream>>>(h, scale, shift, typeStart, y16, n);
        const ushort* wconv = pw_conv + (size_t)l * 640 * 128;
        for (int q0 = 0; q0 < n; q0 += CHK) {
            const int q1 = min(n, q0 + CHK);
            k_agg4<<<(q1 - q0 + 3) / 4, 256, 0, stream>>>(y16, rowp2, csr, buf, q0, q1);
            k_mf<640, 128, false, false, true, true, false, false, true, 2>
                <<<(q1 - q0 + 127) / 128, 256, 0, stream>>>(
                    nullptr, buf, y16, wconv, rg_bias + (size_t)l * CC, nullptr, nullptr,
                    typeStart, h, h16, SS(s_mn), q0, q0, q1);
        }

        k_coef<<<1, 512, 0, stream>>>(SS(s_mn), typeStart, mn_g + (size_t)l * TT * CC,
                                      mn_b + (size_t)l * TT * CC, scale, shift, CC);
        k_mf<128, 256, true, true, true, false, true, true, true, 1><<<dim3(gmx, 2, 2), 256, 0, stream>>>(
            nullptr, h16, nullptr, pw_mw0 + (size_t)l * 2 * 128 * 256, mb0 + (size_t)l * TT * HH,
            scale, shift, typeStart, nullptr, A256b, SS(s_mg), 0, 0, n);
        k_coef<<<1, 512, 0, stream>>>(SS(s_mg), typeStart, mg0 + (size_t)l * TT * HH,
                                      mbe0 + (size_t)l * TT * HH, scale, shift, HH);
        if (l == 0)
            k_mf<256, 128, true, true, true, false, true, true, true, 2><<<dim3(gmx, 2, 1), 256, 0, stream>>>(
                nullptr, A256b, nullptr, pw_mw1 + (size_t)l * 2 * 256 * 128, mb1 + (size_t)l * TT * CC,
                scale, shift, typeStart, h, h16, SS(s_nx), 0, 0, n);
        else
            k_mf<256, 128, true, true, true, false, true, true, false, 2><<<dim3(gmx, 2, 1), 256, 0, stream>>>(
                nullptr, A256b, nullptr, pw_mw1 + (size_t)l * 2 * 256 * 128, mb1 + (size_t)l * TT * CC,
                scale, shift, typeStart, h, h16, nullptr, 0, 0, n);
    }

    // ---- readout ----
    k_mf<128, 256, true, true, true, false, false, true, true, 1><<<dim3(gmx, 2, 2), 256, 0, stream>>>(
        nullptr, h16, nullptr, pw_ro0, ro_b0, nullptr, nullptr, typeStart, nullptr, A256b, SS(8), 0, 0, n);
    k_coef<<<1, 512, 0, stream>>>(SS(8), typeStart, ro_g0, ro_be0, scale, shift, HH);
    k_ro1<<<(n + 63) / 64, 256, 0, stream>>>(A256b, perm, typeStart, ro_w1, ro_b1, scale, shift, out, n);
}